// Round 1
// baseline (5648.573 us; speedup 1.0000x reference)
//
#include <hip/hip_runtime.h>
#include <math.h>

#define Bdim 8
#define Ldim 1024
#define Pdim 64
#define Hdim 512
#define NLdim 4
#define DIN 1024
#define NST 16
#define DTR 32
#define Mrows (Bdim * Ldim)   // 8192

// ---------------------------------------------------------------------------
// minmax-normalize + LayerNorm, one wave (64 lanes) per row of 64 elements
// ---------------------------------------------------------------------------
__global__ __launch_bounds__(256) void ln_kernel(
    const float* __restrict__ x, const float* __restrict__ g,
    const float* __restrict__ bta, float* __restrict__ xl) {
  int row = blockIdx.x * 4 + (threadIdx.x >> 6);
  int lane = threadIdx.x & 63;
  float v = x[(size_t)row * Pdim + lane];
  float mn = v, mx = v;
  #pragma unroll
  for (int m = 1; m < 64; m <<= 1) {
    mn = fminf(mn, __shfl_xor(mn, m, 64));
    mx = fmaxf(mx, __shfl_xor(mx, m, 64));
  }
  float xn = (v - mn) / (mx - mn + 1e-6f);
  float s = xn, s2 = xn * xn;
  #pragma unroll
  for (int m = 1; m < 64; m <<= 1) {
    s += __shfl_xor(s, m, 64);
    s2 += __shfl_xor(s2, m, 64);
  }
  float mu = s * (1.f / 64.f);
  float var = s2 * (1.f / 64.f) - mu * mu;
  float out = (xn - mu) * rsqrtf(var + 1e-5f) * g[lane] + bta[lane];
  xl[(size_t)row * Pdim + lane] = out;
}

// ---------------------------------------------------------------------------
// Generic fp32 GEMM: C(M,N;ldc) = A(M,K;lda) * Bw(N,K)^T [+ bias] [act]
// 128x128 tile, BK=16, 256 threads, 8x8 per thread. M multiple of 128.
// act: 0 = none, 1 = softplus
// ---------------------------------------------------------------------------
#define BM 128
#define BN 128
#define BK 16

__global__ __launch_bounds__(256) void gemm_kernel(
    const float* __restrict__ A, int lda, const float* __restrict__ Bw,
    float* __restrict__ C, int ldc, int Nx, int K,
    const float* __restrict__ bias, int act) {
  __shared__ float As[BK][BM];
  __shared__ float Bs[BK][BN];
  int tid = threadIdx.x;
  int tx = tid & 15, ty = tid >> 4;
  int row0 = blockIdx.y * BM;
  int col0 = blockIdx.x * BN;

  float acc[8][8];
  #pragma unroll
  for (int i = 0; i < 8; ++i)
    #pragma unroll
    for (int j = 0; j < 8; ++j) acc[i][j] = 0.f;

  int lr = tid >> 1;        // 0..127
  int lk = (tid & 1) * 8;   // 0 or 8

  for (int k0 = 0; k0 < K; k0 += BK) {
    const float* ap = A + (size_t)(row0 + lr) * lda + (k0 + lk);
    float4 a0 = *(const float4*)ap;
    float4 a1 = *(const float4*)(ap + 4);
    int bn = col0 + lr;
    float4 b0 = make_float4(0.f, 0.f, 0.f, 0.f);
    float4 b1 = make_float4(0.f, 0.f, 0.f, 0.f);
    if (bn < Nx) {
      const float* bp = Bw + (size_t)bn * K + (k0 + lk);
      b0 = *(const float4*)bp;
      b1 = *(const float4*)(bp + 4);
    }
    __syncthreads();  // previous tile's compute done
    As[lk + 0][lr] = a0.x; As[lk + 1][lr] = a0.y;
    As[lk + 2][lr] = a0.z; As[lk + 3][lr] = a0.w;
    As[lk + 4][lr] = a1.x; As[lk + 5][lr] = a1.y;
    As[lk + 6][lr] = a1.z; As[lk + 7][lr] = a1.w;
    Bs[lk + 0][lr] = b0.x; Bs[lk + 1][lr] = b0.y;
    Bs[lk + 2][lr] = b0.z; Bs[lk + 3][lr] = b0.w;
    Bs[lk + 4][lr] = b1.x; Bs[lk + 5][lr] = b1.y;
    Bs[lk + 6][lr] = b1.z; Bs[lk + 7][lr] = b1.w;
    __syncthreads();
    #pragma unroll
    for (int kk = 0; kk < BK; ++kk) {
      float af[8], bf[8];
      *(float4*)(af)     = *(const float4*)(&As[kk][ty * 8]);
      *(float4*)(af + 4) = *(const float4*)(&As[kk][ty * 8 + 4]);
      *(float4*)(bf)     = *(const float4*)(&Bs[kk][tx * 8]);
      *(float4*)(bf + 4) = *(const float4*)(&Bs[kk][tx * 8 + 4]);
      #pragma unroll
      for (int i = 0; i < 8; ++i)
        #pragma unroll
        for (int j = 0; j < 8; ++j)
          acc[i][j] = fmaf(af[i], bf[j], acc[i][j]);
    }
  }
  __syncthreads();

  #pragma unroll
  for (int i = 0; i < 8; ++i) {
    int r = row0 + ty * 8 + i;
    float* cp = C + (size_t)r * ldc + col0 + tx * 8;
    #pragma unroll
    for (int j = 0; j < 8; ++j) {
      int c = col0 + tx * 8 + j;
      if (c < Nx) {
        float v = acc[i][j];
        if (bias) v += bias[c];
        if (act == 1) v = fmaxf(v, 0.f) + log1pf(expf(-fabsf(v)));  // softplus
        cp[j] = v;
      }
    }
  }
}

// ---------------------------------------------------------------------------
// causal depthwise conv (k=4) + bias + SiLU. Reads xc = xz[:, 0:DIN].
// ---------------------------------------------------------------------------
__global__ __launch_bounds__(256) void conv_kernel(
    const float* __restrict__ xz, const float* __restrict__ cw,
    const float* __restrict__ cb, float* __restrict__ u) {
  int idx = blockIdx.x * 256 + threadIdx.x;  // m*DIN + d
  int d = idx & (DIN - 1);
  int m = idx >> 10;
  int t = m & (Ldim - 1);
  float w0 = cw[d * 4 + 0], w1 = cw[d * 4 + 1], w2 = cw[d * 4 + 2],
        w3 = cw[d * 4 + 3];
  float acc = cb[d];
  if (t >= 3) acc = fmaf(xz[(size_t)(m - 3) * 2048 + d], w0, acc);
  if (t >= 2) acc = fmaf(xz[(size_t)(m - 2) * 2048 + d], w1, acc);
  if (t >= 1) acc = fmaf(xz[(size_t)(m - 1) * 2048 + d], w2, acc);
  acc = fmaf(xz[(size_t)m * 2048 + d], w3, acc);
  u[(size_t)m * DIN + d] = acc / (1.f + expf(-acc));  // silu
}

// ---------------------------------------------------------------------------
// selective scan: 16 lanes per (b,d) chain, one lane per state n.
// delta lives in xz[:, 0:DIN]; z in xz[:, DIN:2*DIN]; Bm/Cm in dbl cols 32/48.
// y overwrites u in place, already gated by silu(z).
// ---------------------------------------------------------------------------
__global__ __launch_bounds__(256) void scan_kernel(
    const float* __restrict__ xz, float* __restrict__ u,
    const float* __restrict__ dbl, const float* __restrict__ A_log,
    const float* __restrict__ Dp) {
  int tid = threadIdx.x;
  int n = tid & 15;
  int chain = blockIdx.x * 16 + (tid >> 4);
  int b = chain >> 10;          // / DIN
  int d = chain & (DIN - 1);
  float Adn = -expf(A_log[d * NST + n]);
  float Dpd = Dp[d];
  float h = 0.f;
  size_t mbase = (size_t)b * Ldim;
  for (int t = 0; t < Ldim; ++t) {
    size_t m = mbase + t;
    float delta = xz[m * 2048 + d];
    float uv = u[m * DIN + d];
    float Bn = dbl[m * 64 + 32 + n];
    float Cn = dbl[m * 64 + 48 + n];
    float dA = expf(delta * Adn);
    h = fmaf(dA, h, (delta * uv) * Bn);
    float p = h * Cn;
    p += __shfl_xor(p, 1, 64);
    p += __shfl_xor(p, 2, 64);
    p += __shfl_xor(p, 4, 64);
    p += __shfl_xor(p, 8, 64);
    if (n == 0) {
      float z = xz[m * 2048 + DIN + d];
      float y = (p + uv * Dpd) * (z / (1.f + expf(-z)));
      u[m * DIN + d] = y;
    }
  }
}

// ---------------------------------------------------------------------------
// maxpool over time, stage 1: per (b, t-chunk of 128) partial max per channel
// ---------------------------------------------------------------------------
__global__ __launch_bounds__(256) void pool1_kernel(
    const float* __restrict__ h, float* __restrict__ pm) {
  int b = blockIdx.x, r = blockIdx.y;
  int tid = threadIdx.x;
  #pragma unroll
  for (int rep = 0; rep < 2; ++rep) {
    int j = tid + rep * 256;
    float mx = -1e30f;
    size_t base = ((size_t)b * Ldim + r * 128) * Hdim + j;
    for (int t = 0; t < 128; ++t) mx = fmaxf(mx, h[base + (size_t)t * Hdim]);
    pm[((size_t)b * 8 + r) * Hdim + j] = mx;
  }
}

// stage 2: reduce partials, dot with fc_w, add fc_b
__global__ __launch_bounds__(256) void pool2_kernel(
    const float* __restrict__ pm, const float* __restrict__ fcw,
    const float* __restrict__ fcb, float* __restrict__ out) {
  int b = blockIdx.x, tid = threadIdx.x;
  float acc = 0.f;
  #pragma unroll
  for (int rep = 0; rep < 2; ++rep) {
    int j = tid + rep * 256;
    float mx = -1e30f;
    for (int r = 0; r < 8; ++r) mx = fmaxf(mx, pm[((size_t)b * 8 + r) * Hdim + j]);
    acc += mx * fcw[j];
  }
  __shared__ float red[256];
  red[tid] = acc;
  __syncthreads();
  for (int s = 128; s > 0; s >>= 1) {
    if (tid < s) red[tid] += red[tid + s];
    __syncthreads();
  }
  if (tid == 0) out[b] = red[0] + fcb[0];
}

// ---------------------------------------------------------------------------
extern "C" void kernel_launch(void* const* d_in, const int* in_sizes, int n_in,
                              void* d_out, int out_size, void* d_ws,
                              size_t ws_size, hipStream_t stream) {
  const float* x         = (const float*)d_in[0];
  const float* ln_g      = (const float*)d_in[1];
  const float* ln_b      = (const float*)d_in[2];
  const float* proj_w    = (const float*)d_in[3];
  const float* proj_b    = (const float*)d_in[4];
  const float* in_proj_w = (const float*)d_in[5];
  const float* conv_w    = (const float*)d_in[6];
  const float* conv_b    = (const float*)d_in[7];
  const float* xproj_w   = (const float*)d_in[8];
  const float* dtproj_w  = (const float*)d_in[9];
  const float* dtproj_b  = (const float*)d_in[10];
  const float* A_log     = (const float*)d_in[11];
  const float* Dp        = (const float*)d_in[12];
  const float* out_pw    = (const float*)d_in[13];
  const float* fc_w      = (const float*)d_in[14];
  const float* fc_b      = (const float*)d_in[15];
  float* out = (float*)d_out;

  float* ws   = (float*)d_ws;
  float* xl   = ws;                                 // M*64
  float* hbuf = xl + (size_t)Mrows * Pdim;          // M*512
  float* xz   = hbuf + (size_t)Mrows * Hdim;        // M*2048 (delta reuses xc half)
  float* ubuf = xz + (size_t)Mrows * 2 * DIN;       // M*1024 (y in place)
  float* dbl  = ubuf + (size_t)Mrows * DIN;         // M*64
  float* pm   = dbl + (size_t)Mrows * 64;           // 8*8*512

  // LN + input projection: h = LN(x) @ proj_w^T + proj_b
  ln_kernel<<<Mrows / 4, 256, 0, stream>>>(x, ln_g, ln_b, xl);
  gemm_kernel<<<dim3(Hdim / BN, Mrows / BM), 256, 0, stream>>>(
      xl, Pdim, proj_w, hbuf, Hdim, Hdim, Pdim, proj_b, 0);

  for (int l = 0; l < NLdim; ++l) {
    const float* w_in = in_proj_w + (size_t)l * 2 * DIN * Hdim;
    const float* cw   = conv_w + (size_t)l * DIN * 4;
    const float* cb   = conv_b + (size_t)l * DIN;
    const float* w_x  = xproj_w + (size_t)l * 64 * DIN;
    const float* w_dt = dtproj_w + (size_t)l * DIN * DTR;
    const float* b_dt = dtproj_b + (size_t)l * DIN;
    const float* Al   = A_log + (size_t)l * DIN * NST;
    const float* Dl   = Dp + (size_t)l * DIN;
    const float* w_o  = out_pw + (size_t)l * Hdim * DIN;

    // xz = h @ w_in^T                    (M, 2048)
    gemm_kernel<<<dim3(2 * DIN / BN, Mrows / BM), 256, 0, stream>>>(
        hbuf, Hdim, w_in, xz, 2 * DIN, 2 * DIN, Hdim, nullptr, 0);
    // u = silu(causal_conv(xc) + cb)     (M, 1024)
    conv_kernel<<<(size_t)Mrows * DIN / 256, 256, 0, stream>>>(xz, cw, cb, ubuf);
    // dbl = u @ w_x^T                    (M, 64)  [dt | Bm | Cm]
    gemm_kernel<<<dim3(1, Mrows / BM), 256, 0, stream>>>(
        ubuf, DIN, w_x, dbl, 64, 64, DIN, nullptr, 0);
    // delta = softplus(dt @ w_dt^T + b_dt) -> xz[:, 0:1024] (xc is dead)
    gemm_kernel<<<dim3(DIN / BN, Mrows / BM), 256, 0, stream>>>(
        dbl, 64, w_dt, xz, 2 * DIN, DIN, DTR, b_dt, 1);
    // selective scan + gate by silu(z); y overwrites u
    scan_kernel<<<Bdim * DIN / 16, 256, 0, stream>>>(xz, ubuf, dbl, Al, Dl);
    // h = y @ w_out^T                    (M, 512)
    gemm_kernel<<<dim3(Hdim / BN, Mrows / BM), 256, 0, stream>>>(
        ubuf, DIN, w_o, hbuf, Hdim, Hdim, DIN, nullptr, 0);
  }

  pool1_kernel<<<dim3(Bdim, 8), 256, 0, stream>>>(hbuf, pm);
  pool2_kernel<<<Bdim, 256, 0, stream>>>(pm, fc_w, fc_b, out);
}

// Round 2
// 2749.748 us; speedup vs baseline: 2.0542x; 2.0542x over previous
//
#include <hip/hip_runtime.h>
#include <math.h>

#define Bdim 8
#define Ldim 1024
#define Pdim 64
#define Hdim 512
#define NLdim 4
#define DIN 1024
#define NST 16
#define DTR 32
#define Mrows (Bdim * Ldim)   // 8192
#define CHUNK 64
#define NCHUNK (Ldim / CHUNK) // 16

// ---------------------------------------------------------------------------
// minmax-normalize + LayerNorm, one wave (64 lanes) per row of 64 elements
// ---------------------------------------------------------------------------
__global__ __launch_bounds__(256) void ln_kernel(
    const float* __restrict__ x, const float* __restrict__ g,
    const float* __restrict__ bta, float* __restrict__ xl) {
  int row = blockIdx.x * 4 + (threadIdx.x >> 6);
  int lane = threadIdx.x & 63;
  float v = x[(size_t)row * Pdim + lane];
  float mn = v, mx = v;
  #pragma unroll
  for (int m = 1; m < 64; m <<= 1) {
    mn = fminf(mn, __shfl_xor(mn, m, 64));
    mx = fmaxf(mx, __shfl_xor(mx, m, 64));
  }
  float xn = (v - mn) / (mx - mn + 1e-6f);
  float s = xn, s2 = xn * xn;
  #pragma unroll
  for (int m = 1; m < 64; m <<= 1) {
    s += __shfl_xor(s, m, 64);
    s2 += __shfl_xor(s2, m, 64);
  }
  float mu = s * (1.f / 64.f);
  float var = s2 * (1.f / 64.f) - mu * mu;
  float out = (xn - mu) * rsqrtf(var + 1e-5f) * g[lane] + bta[lane];
  xl[(size_t)row * Pdim + lane] = out;
}

// ---------------------------------------------------------------------------
// Generic fp32 GEMM: C(M,N;ldc) = A(M,K;lda) * Bw(N,K)^T [+ bias] [act]
// 128x128 tile, BK=16, 256 threads, 8x8 per thread. M multiple of 128.
// act: 0 = none, 1 = softplus
// ---------------------------------------------------------------------------
#define BM 128
#define BN 128
#define BK 16

__global__ __launch_bounds__(256) void gemm_kernel(
    const float* __restrict__ A, int lda, const float* __restrict__ Bw,
    float* __restrict__ C, int ldc, int Nx, int K,
    const float* __restrict__ bias, int act) {
  __shared__ float As[BK][BM];
  __shared__ float Bs[BK][BN];
  int tid = threadIdx.x;
  int tx = tid & 15, ty = tid >> 4;
  int row0 = blockIdx.y * BM;
  int col0 = blockIdx.x * BN;

  float acc[8][8];
  #pragma unroll
  for (int i = 0; i < 8; ++i)
    #pragma unroll
    for (int j = 0; j < 8; ++j) acc[i][j] = 0.f;

  int lr = tid >> 1;        // 0..127
  int lk = (tid & 1) * 8;   // 0 or 8

  for (int k0 = 0; k0 < K; k0 += BK) {
    const float* ap = A + (size_t)(row0 + lr) * lda + (k0 + lk);
    float4 a0 = *(const float4*)ap;
    float4 a1 = *(const float4*)(ap + 4);
    int bn = col0 + lr;
    float4 b0 = make_float4(0.f, 0.f, 0.f, 0.f);
    float4 b1 = make_float4(0.f, 0.f, 0.f, 0.f);
    if (bn < Nx) {
      const float* bp = Bw + (size_t)bn * K + (k0 + lk);
      b0 = *(const float4*)bp;
      b1 = *(const float4*)(bp + 4);
    }
    __syncthreads();  // previous tile's compute done
    As[lk + 0][lr] = a0.x; As[lk + 1][lr] = a0.y;
    As[lk + 2][lr] = a0.z; As[lk + 3][lr] = a0.w;
    As[lk + 4][lr] = a1.x; As[lk + 5][lr] = a1.y;
    As[lk + 6][lr] = a1.z; As[lk + 7][lr] = a1.w;
    Bs[lk + 0][lr] = b0.x; Bs[lk + 1][lr] = b0.y;
    Bs[lk + 2][lr] = b0.z; Bs[lk + 3][lr] = b0.w;
    Bs[lk + 4][lr] = b1.x; Bs[lk + 5][lr] = b1.y;
    Bs[lk + 6][lr] = b1.z; Bs[lk + 7][lr] = b1.w;
    __syncthreads();
    #pragma unroll
    for (int kk = 0; kk < BK; ++kk) {
      float af[8], bf[8];
      *(float4*)(af)     = *(const float4*)(&As[kk][ty * 8]);
      *(float4*)(af + 4) = *(const float4*)(&As[kk][ty * 8 + 4]);
      *(float4*)(bf)     = *(const float4*)(&Bs[kk][tx * 8]);
      *(float4*)(bf + 4) = *(const float4*)(&Bs[kk][tx * 8 + 4]);
      #pragma unroll
      for (int i = 0; i < 8; ++i)
        #pragma unroll
        for (int j = 0; j < 8; ++j)
          acc[i][j] = fmaf(af[i], bf[j], acc[i][j]);
    }
  }
  __syncthreads();

  #pragma unroll
  for (int i = 0; i < 8; ++i) {
    int r = row0 + ty * 8 + i;
    float* cp = C + (size_t)r * ldc + col0 + tx * 8;
    #pragma unroll
    for (int j = 0; j < 8; ++j) {
      int c = col0 + tx * 8 + j;
      if (c < Nx) {
        float v = acc[i][j];
        if (bias) v += bias[c];
        if (act == 1) v = fmaxf(v, 0.f) + log1pf(expf(-fabsf(v)));  // softplus
        cp[j] = v;
      }
    }
  }
}

// ---------------------------------------------------------------------------
// causal depthwise conv (k=4) + bias + SiLU. Reads xc = xz[:, 0:DIN].
// ---------------------------------------------------------------------------
__global__ __launch_bounds__(256) void conv_kernel(
    const float* __restrict__ xz, const float* __restrict__ cw,
    const float* __restrict__ cb, float* __restrict__ u) {
  int idx = blockIdx.x * 256 + threadIdx.x;  // m*DIN + d
  int d = idx & (DIN - 1);
  int m = idx >> 10;
  int t = m & (Ldim - 1);
  float w0 = cw[d * 4 + 0], w1 = cw[d * 4 + 1], w2 = cw[d * 4 + 2],
        w3 = cw[d * 4 + 3];
  float acc = cb[d];
  if (t >= 3) acc = fmaf(xz[(size_t)(m - 3) * 2048 + d], w0, acc);
  if (t >= 2) acc = fmaf(xz[(size_t)(m - 2) * 2048 + d], w1, acc);
  if (t >= 1) acc = fmaf(xz[(size_t)(m - 1) * 2048 + d], w2, acc);
  acc = fmaf(xz[(size_t)m * 2048 + d], w3, acc);
  u[(size_t)m * DIN + d] = acc / (1.f + __expf(-acc));  // silu
}

// ---------------------------------------------------------------------------
// Chunked selective scan, pass 1: per (b,d,chunk) compute
//   Q = chunk-local scan from h=0, P = prod(a_t)  for each of 16 states.
// Layout of Hsum/Aprod: [b][chunk][n][d]  (coalesced over d)
// ---------------------------------------------------------------------------
__global__ __launch_bounds__(256) void scan1_kernel(
    const float* __restrict__ xz, const float* __restrict__ u,
    const float* __restrict__ dbl, const float* __restrict__ A_log,
    float* __restrict__ Hsum, float* __restrict__ Aprod) {
  __shared__ float Bsh[CHUNK][NST];
  int tid = threadIdx.x;
  int d = blockIdx.x * 256 + tid;
  int c = blockIdx.y;
  int b = blockIdx.z;
  size_t mbase = (size_t)b * Ldim + (size_t)c * CHUNK;
  for (int i = tid; i < CHUNK * NST; i += 256) {
    int t = i >> 4, n = i & 15;
    Bsh[t][n] = dbl[(mbase + t) * 64 + 32 + n];
  }
  float Adn[NST];
  #pragma unroll
  for (int n = 0; n < NST; ++n) Adn[n] = -__expf(A_log[d * NST + n]);
  float h[NST], ap[NST];
  #pragma unroll
  for (int n = 0; n < NST; ++n) { h[n] = 0.f; ap[n] = 1.f; }
  __syncthreads();
  for (int t = 0; t < CHUNK; ++t) {
    size_t m = mbase + t;
    float delta = xz[m * 2048 + d];
    float uv = u[m * DIN + d];
    float du = delta * uv;
    #pragma unroll
    for (int n = 0; n < NST; ++n) {
      float a = __expf(delta * Adn[n]);
      h[n] = fmaf(a, h[n], du * Bsh[t][n]);
      ap[n] *= a;
    }
  }
  size_t base = ((size_t)(b * NCHUNK + c) * NST) * DIN + d;
  #pragma unroll
  for (int n = 0; n < NST; ++n) {
    Hsum[base + (size_t)n * DIN] = h[n];
    Aprod[base + (size_t)n * DIN] = ap[n];
  }
}

// ---------------------------------------------------------------------------
// pass 2: serial carry over the 16 chunks, one thread per (b,n,d).
// Overwrites Hsum with the EXCLUSIVE carry (h at chunk start).
// ---------------------------------------------------------------------------
__global__ __launch_bounds__(256) void scan2_kernel(
    float* __restrict__ Hsum, const float* __restrict__ Aprod) {
  int idx = blockIdx.x * 256 + threadIdx.x;
  int d = idx & (DIN - 1);
  int bn = idx >> 10;
  int n = bn & 15;
  int b = bn >> 4;
  float carry = 0.f;
  for (int c = 0; c < NCHUNK; ++c) {
    size_t off = ((size_t)((b * NCHUNK + c) * NST + n)) * DIN + d;
    float hs = Hsum[off];
    float apv = Aprod[off];
    Hsum[off] = carry;
    carry = fmaf(apv, carry, hs);
  }
}

// ---------------------------------------------------------------------------
// pass 3: replay chunk from correct h_start, y = C·h + u*Dp, gate silu(z).
// y overwrites u in place.
// ---------------------------------------------------------------------------
__global__ __launch_bounds__(256) void scan3_kernel(
    const float* __restrict__ xz, float* __restrict__ u,
    const float* __restrict__ dbl, const float* __restrict__ A_log,
    const float* __restrict__ Dp, const float* __restrict__ Hstart) {
  __shared__ float Bsh[CHUNK][NST];
  __shared__ float Csh[CHUNK][NST];
  int tid = threadIdx.x;
  int d = blockIdx.x * 256 + tid;
  int c = blockIdx.y;
  int b = blockIdx.z;
  size_t mbase = (size_t)b * Ldim + (size_t)c * CHUNK;
  for (int i = tid; i < CHUNK * NST; i += 256) {
    int t = i >> 4, n = i & 15;
    Bsh[t][n] = dbl[(mbase + t) * 64 + 32 + n];
    Csh[t][n] = dbl[(mbase + t) * 64 + 48 + n];
  }
  float Adn[NST];
  #pragma unroll
  for (int n = 0; n < NST; ++n) Adn[n] = -__expf(A_log[d * NST + n]);
  float h[NST];
  size_t base = ((size_t)(b * NCHUNK + c) * NST) * DIN + d;
  #pragma unroll
  for (int n = 0; n < NST; ++n) h[n] = Hstart[base + (size_t)n * DIN];
  float Dpd = Dp[d];
  __syncthreads();
  for (int t = 0; t < CHUNK; ++t) {
    size_t m = mbase + t;
    float delta = xz[m * 2048 + d];
    float uv = u[m * DIN + d];
    float du = delta * uv;
    float y = 0.f;
    #pragma unroll
    for (int n = 0; n < NST; ++n) {
      float a = __expf(delta * Adn[n]);
      h[n] = fmaf(a, h[n], du * Bsh[t][n]);
      y = fmaf(h[n], Csh[t][n], y);
    }
    float z = xz[m * 2048 + DIN + d];
    float sz = z / (1.f + __expf(-z));
    u[m * DIN + d] = (y + uv * Dpd) * sz;
  }
}

// ---------------------------------------------------------------------------
// maxpool over time, stage 1: per (b, t-chunk of 128) partial max per channel
// ---------------------------------------------------------------------------
__global__ __launch_bounds__(256) void pool1_kernel(
    const float* __restrict__ h, float* __restrict__ pm) {
  int b = blockIdx.x, r = blockIdx.y;
  int tid = threadIdx.x;
  #pragma unroll
  for (int rep = 0; rep < 2; ++rep) {
    int j = tid + rep * 256;
    float mx = -1e30f;
    size_t base = ((size_t)b * Ldim + r * 128) * Hdim + j;
    for (int t = 0; t < 128; ++t) mx = fmaxf(mx, h[base + (size_t)t * Hdim]);
    pm[((size_t)b * 8 + r) * Hdim + j] = mx;
  }
}

// stage 2: reduce partials, dot with fc_w, add fc_b
__global__ __launch_bounds__(256) void pool2_kernel(
    const float* __restrict__ pm, const float* __restrict__ fcw,
    const float* __restrict__ fcb, float* __restrict__ out) {
  int b = blockIdx.x, tid = threadIdx.x;
  float acc = 0.f;
  #pragma unroll
  for (int rep = 0; rep < 2; ++rep) {
    int j = tid + rep * 256;
    float mx = -1e30f;
    for (int r = 0; r < 8; ++r) mx = fmaxf(mx, pm[((size_t)b * 8 + r) * Hdim + j]);
    acc += mx * fcw[j];
  }
  __shared__ float red[256];
  red[tid] = acc;
  __syncthreads();
  for (int s = 128; s > 0; s >>= 1) {
    if (tid < s) red[tid] += red[tid + s];
    __syncthreads();
  }
  if (tid == 0) out[b] = red[0] + fcb[0];
}

// ---------------------------------------------------------------------------
extern "C" void kernel_launch(void* const* d_in, const int* in_sizes, int n_in,
                              void* d_out, int out_size, void* d_ws,
                              size_t ws_size, hipStream_t stream) {
  const float* x         = (const float*)d_in[0];
  const float* ln_g      = (const float*)d_in[1];
  const float* ln_b      = (const float*)d_in[2];
  const float* proj_w    = (const float*)d_in[3];
  const float* proj_b    = (const float*)d_in[4];
  const float* in_proj_w = (const float*)d_in[5];
  const float* conv_w    = (const float*)d_in[6];
  const float* conv_b    = (const float*)d_in[7];
  const float* xproj_w   = (const float*)d_in[8];
  const float* dtproj_w  = (const float*)d_in[9];
  const float* dtproj_b  = (const float*)d_in[10];
  const float* A_log     = (const float*)d_in[11];
  const float* Dp        = (const float*)d_in[12];
  const float* out_pw    = (const float*)d_in[13];
  const float* fc_w      = (const float*)d_in[14];
  const float* fc_b      = (const float*)d_in[15];
  float* out = (float*)d_out;

  float* ws   = (float*)d_ws;
  float* xl   = ws;                                 // M*64
  float* hbuf = xl + (size_t)Mrows * Pdim;          // M*512
  float* xz   = hbuf + (size_t)Mrows * Hdim;        // M*2048 (delta reuses xc half)
  float* ubuf = xz + (size_t)Mrows * 2 * DIN;       // M*1024 (y in place)
  float* dbl  = ubuf + (size_t)Mrows * DIN;         // M*64
  float* pm   = dbl + (size_t)Mrows * 64;           // 8*8*512
  // Hsum/Aprod overlay hbuf (dead between in_proj and out_proj):
  // each B*NCHUNK*NST*DIN = 2,097,152 floats; 2 of them = exactly M*Hdim.
  float* Hsum  = hbuf;
  float* Aprod = hbuf + (size_t)Bdim * NCHUNK * NST * DIN;

  // LN + input projection: h = LN(x) @ proj_w^T + proj_b
  ln_kernel<<<Mrows / 4, 256, 0, stream>>>(x, ln_g, ln_b, xl);
  gemm_kernel<<<dim3(Hdim / BN, Mrows / BM), 256, 0, stream>>>(
      xl, Pdim, proj_w, hbuf, Hdim, Hdim, Pdim, proj_b, 0);

  for (int l = 0; l < NLdim; ++l) {
    const float* w_in = in_proj_w + (size_t)l * 2 * DIN * Hdim;
    const float* cw   = conv_w + (size_t)l * DIN * 4;
    const float* cb   = conv_b + (size_t)l * DIN;
    const float* w_x  = xproj_w + (size_t)l * 64 * DIN;
    const float* w_dt = dtproj_w + (size_t)l * DIN * DTR;
    const float* b_dt = dtproj_b + (size_t)l * DIN;
    const float* Al   = A_log + (size_t)l * DIN * NST;
    const float* Dl   = Dp + (size_t)l * DIN;
    const float* w_o  = out_pw + (size_t)l * Hdim * DIN;

    // xz = h @ w_in^T                    (M, 2048)
    gemm_kernel<<<dim3(2 * DIN / BN, Mrows / BM), 256, 0, stream>>>(
        hbuf, Hdim, w_in, xz, 2 * DIN, 2 * DIN, Hdim, nullptr, 0);
    // u = silu(causal_conv(xc) + cb)     (M, 1024)
    conv_kernel<<<(size_t)Mrows * DIN / 256, 256, 0, stream>>>(xz, cw, cb, ubuf);
    // dbl = u @ w_x^T                    (M, 64)  [dt | Bm | Cm]
    gemm_kernel<<<dim3(1, Mrows / BM), 256, 0, stream>>>(
        ubuf, DIN, w_x, dbl, 64, 64, DIN, nullptr, 0);
    // delta = softplus(dt @ w_dt^T + b_dt) -> xz[:, 0:1024] (xc is dead)
    gemm_kernel<<<dim3(DIN / BN, Mrows / BM), 256, 0, stream>>>(
        dbl, 64, w_dt, xz, 2 * DIN, DIN, DTR, b_dt, 1);
    // chunked selective scan (3 passes); y overwrites u, gated by silu(z)
    scan1_kernel<<<dim3(DIN / 256, NCHUNK, Bdim), 256, 0, stream>>>(
        xz, ubuf, dbl, Al, Hsum, Aprod);
    scan2_kernel<<<Bdim * NST * DIN / 256, 256, 0, stream>>>(Hsum, Aprod);
    scan3_kernel<<<dim3(DIN / 256, NCHUNK, Bdim), 256, 0, stream>>>(
        xz, ubuf, dbl, Al, Dl, Hsum);
    // h = y @ w_out^T                    (M, 512)
    gemm_kernel<<<dim3(Hdim / BN, Mrows / BM), 256, 0, stream>>>(
        ubuf, DIN, w_o, hbuf, Hdim, Hdim, DIN, nullptr, 0);
  }

  pool1_kernel<<<dim3(Bdim, 8), 256, 0, stream>>>(hbuf, pm);
  pool2_kernel<<<Bdim, 256, 0, stream>>>(pm, fc_w, fc_b, out);
}

// Round 3
// 2049.508 us; speedup vs baseline: 2.7561x; 1.3417x over previous
//
#include <hip/hip_runtime.h>
#include <math.h>

#define Bdim 8
#define Ldim 1024
#define Pdim 64
#define Hdim 512
#define NLdim 4
#define DIN 1024
#define NST 16
#define DTR 32
#define Mrows (Bdim * Ldim)   // 8192
#define CHUNK 64
#define NCHUNK (Ldim / CHUNK) // 16

typedef unsigned int u32;
typedef __attribute__((ext_vector_type(8))) short bf16x8;
typedef __attribute__((ext_vector_type(4))) float f32x4;

__device__ __forceinline__ short f2bf(float f) {
  union { float f; u32 u; } v; v.f = f;
  u32 r = v.u + 0x7fffu + ((v.u >> 16) & 1u);
  return (short)(r >> 16);
}
__device__ __forceinline__ float bf2f(short h) {
  union { u32 u; float f; } v; v.u = ((u32)(unsigned short)h) << 16;
  return v.f;
}
__device__ __forceinline__ void gld16(const short* g, short* l) {
  __builtin_amdgcn_global_load_lds(
      (const __attribute__((address_space(1))) void*)g,
      (__attribute__((address_space(3))) void*)l, 16, 0, 0);
}

// ---------------------------------------------------------------------------
// minmax-normalize + LayerNorm, one wave (64 lanes) per row of 64 elements
// ---------------------------------------------------------------------------
__global__ __launch_bounds__(256) void ln_kernel(
    const float* __restrict__ x, const float* __restrict__ g,
    const float* __restrict__ bta, float* __restrict__ xl) {
  int row = blockIdx.x * 4 + (threadIdx.x >> 6);
  int lane = threadIdx.x & 63;
  float v = x[(size_t)row * Pdim + lane];
  float mn = v, mx = v;
  #pragma unroll
  for (int m = 1; m < 64; m <<= 1) {
    mn = fminf(mn, __shfl_xor(mn, m, 64));
    mx = fmaxf(mx, __shfl_xor(mx, m, 64));
  }
  float xn = (v - mn) / (mx - mn + 1e-6f);
  float s = xn, s2 = xn * xn;
  #pragma unroll
  for (int m = 1; m < 64; m <<= 1) {
    s += __shfl_xor(s, m, 64);
    s2 += __shfl_xor(s2, m, 64);
  }
  float mu = s * (1.f / 64.f);
  float var = s2 * (1.f / 64.f) - mu * mu;
  float out = (xn - mu) * rsqrtf(var + 1e-5f) * g[lane] + bta[lane];
  xl[(size_t)row * Pdim + lane] = out;
}

// ---------------------------------------------------------------------------
// split fp32 -> concatenated bf16 triple.  wstyle=0: [hi|lo|hi] (activations)
// wstyle=1: [hi|hi|lo] (weights).  K = 1<<kshift, 2 elements per thread.
// ---------------------------------------------------------------------------
__global__ __launch_bounds__(256) void split_bf16_kernel(
    const float* __restrict__ X, short* __restrict__ Xb, int kshift,
    int wstyle) {
  int idx = blockIdx.x * 256 + threadIdx.x;
  int K = 1 << kshift;
  int m = idx >> (kshift - 1);
  int k2 = (idx & ((K >> 1) - 1)) << 1;
  float2 v = *(const float2*)&X[((size_t)m << kshift) + k2];
  short h0 = f2bf(v.x), h1 = f2bf(v.y);
  short l0 = f2bf(v.x - bf2f(h0)), l1 = f2bf(v.y - bf2f(h1));
  short2 hh; hh.x = h0; hh.y = h1;
  short2 ll; ll.x = l0; ll.y = l1;
  size_t base = (size_t)m * 3 * K + k2;
  *(short2*)&Xb[base] = hh;
  *(short2*)&Xb[base + K] = wstyle ? hh : ll;
  *(short2*)&Xb[base + 2 * K] = wstyle ? ll : hh;
}

// ---------------------------------------------------------------------------
// bf16 MFMA GEMM (m97 structure): C(M,Nx) = Ab(M,Kp) * Wb(Nx,Kp)^T, fp32 out.
// 128x128 tile, BK=32, 256 threads (4 waves, each 64x64 via 4x4 of 16x16x32).
// Kp % 32 == 0, Nx % 128 == 0, M % 128 == 0.
// ---------------------------------------------------------------------------
__global__ __launch_bounds__(256) void gemm_mfma(
    const short* __restrict__ Ab, const short* __restrict__ Wb,
    float* __restrict__ C, int Kp, int ldc) {
  __shared__ short As[128 * 32];
  __shared__ short Bs[128 * 32];
  int tid = threadIdx.x;
  int lane = tid & 63;
  int wave = tid >> 6;
  int quad = lane >> 4, l16 = lane & 15;
  int wm = (wave & 1) * 64, wn = (wave >> 1) * 64;
  int row0 = blockIdx.y * 128, col0 = blockIdx.x * 128;

  f32x4 acc[4][4];
  #pragma unroll
  for (int i = 0; i < 4; ++i)
    #pragma unroll
    for (int j = 0; j < 4; ++j) acc[i][j] = (f32x4){0.f, 0.f, 0.f, 0.f};

  int lin0 = tid, lin1 = tid + 256;
  const short* gA0 = Ab + (size_t)(row0 + (lin0 >> 2)) * Kp + ((lin0 & 3) << 3);
  const short* gA1 = Ab + (size_t)(row0 + (lin1 >> 2)) * Kp + ((lin1 & 3) << 3);
  const short* gB0 = Wb + (size_t)(col0 + (lin0 >> 2)) * Kp + ((lin0 & 3) << 3);
  const short* gB1 = Wb + (size_t)(col0 + (lin1 >> 2)) * Kp + ((lin1 & 3) << 3);
  short* lA0 = &As[lin0 * 8];
  short* lA1 = &As[lin1 * 8];
  short* lB0 = &Bs[lin0 * 8];
  short* lB1 = &Bs[lin1 * 8];

  for (int k0 = 0; k0 < Kp; k0 += 32) {
    __syncthreads();
    gld16(gA0 + k0, lA0);
    gld16(gA1 + k0, lA1);
    gld16(gB0 + k0, lB0);
    gld16(gB1 + k0, lB1);
    __syncthreads();
    bf16x8 af[4], bfr[4];
    #pragma unroll
    for (int t = 0; t < 4; ++t) {
      af[t]  = *(const bf16x8*)&As[(wm + t * 16 + l16) * 32 + quad * 8];
      bfr[t] = *(const bf16x8*)&Bs[(wn + t * 16 + l16) * 32 + quad * 8];
    }
    #pragma unroll
    for (int tm = 0; tm < 4; ++tm)
      #pragma unroll
      for (int tn = 0; tn < 4; ++tn)
        acc[tm][tn] = __builtin_amdgcn_mfma_f32_16x16x32_bf16(
            af[tm], bfr[tn], acc[tm][tn], 0, 0, 0);
  }

  #pragma unroll
  for (int tm = 0; tm < 4; ++tm) {
    #pragma unroll
    for (int r = 0; r < 4; ++r) {
      int row = row0 + wm + tm * 16 + quad * 4 + r;
      float* cp = C + (size_t)row * ldc + col0 + wn + l16;
      #pragma unroll
      for (int tn = 0; tn < 4; ++tn) cp[tn * 16] = acc[tm][tn][r];
    }
  }
}

// ---------------------------------------------------------------------------
// Generic fp32 GEMM (kept for proj / x_proj / dt_proj):
// C(M,N;ldc) = A(M,K;lda) * Bw(N,K)^T [+ bias] [act]; act 1 = softplus
// ---------------------------------------------------------------------------
#define BM 128
#define BN 128
#define BK 16

__global__ __launch_bounds__(256) void gemm_kernel(
    const float* __restrict__ A, int lda, const float* __restrict__ Bw,
    float* __restrict__ C, int ldc, int Nx, int K,
    const float* __restrict__ bias, int act) {
  __shared__ float As[BK][BM];
  __shared__ float Bs[BK][BN];
  int tid = threadIdx.x;
  int tx = tid & 15, ty = tid >> 4;
  int row0 = blockIdx.y * BM;
  int col0 = blockIdx.x * BN;

  float acc[8][8];
  #pragma unroll
  for (int i = 0; i < 8; ++i)
    #pragma unroll
    for (int j = 0; j < 8; ++j) acc[i][j] = 0.f;

  int lr = tid >> 1;
  int lk = (tid & 1) * 8;

  for (int k0 = 0; k0 < K; k0 += BK) {
    const float* ap = A + (size_t)(row0 + lr) * lda + (k0 + lk);
    float4 a0 = *(const float4*)ap;
    float4 a1 = *(const float4*)(ap + 4);
    int bn = col0 + lr;
    float4 b0 = make_float4(0.f, 0.f, 0.f, 0.f);
    float4 b1 = make_float4(0.f, 0.f, 0.f, 0.f);
    if (bn < Nx) {
      const float* bp = Bw + (size_t)bn * K + (k0 + lk);
      b0 = *(const float4*)bp;
      b1 = *(const float4*)(bp + 4);
    }
    __syncthreads();
    As[lk + 0][lr] = a0.x; As[lk + 1][lr] = a0.y;
    As[lk + 2][lr] = a0.z; As[lk + 3][lr] = a0.w;
    As[lk + 4][lr] = a1.x; As[lk + 5][lr] = a1.y;
    As[lk + 6][lr] = a1.z; As[lk + 7][lr] = a1.w;
    Bs[lk + 0][lr] = b0.x; Bs[lk + 1][lr] = b0.y;
    Bs[lk + 2][lr] = b0.z; Bs[lk + 3][lr] = b0.w;
    Bs[lk + 4][lr] = b1.x; Bs[lk + 5][lr] = b1.y;
    Bs[lk + 6][lr] = b1.z; Bs[lk + 7][lr] = b1.w;
    __syncthreads();
    #pragma unroll
    for (int kk = 0; kk < BK; ++kk) {
      float af[8], bf[8];
      *(float4*)(af)     = *(const float4*)(&As[kk][ty * 8]);
      *(float4*)(af + 4) = *(const float4*)(&As[kk][ty * 8 + 4]);
      *(float4*)(bf)     = *(const float4*)(&Bs[kk][tx * 8]);
      *(float4*)(bf + 4) = *(const float4*)(&Bs[kk][tx * 8 + 4]);
      #pragma unroll
      for (int i = 0; i < 8; ++i)
        #pragma unroll
        for (int j = 0; j < 8; ++j)
          acc[i][j] = fmaf(af[i], bf[j], acc[i][j]);
    }
  }
  __syncthreads();

  #pragma unroll
  for (int i = 0; i < 8; ++i) {
    int r = row0 + ty * 8 + i;
    float* cp = C + (size_t)r * ldc + col0 + tx * 8;
    #pragma unroll
    for (int j = 0; j < 8; ++j) {
      int c = col0 + tx * 8 + j;
      if (c < Nx) {
        float v = acc[i][j];
        if (bias) v += bias[c];
        if (act == 1) v = fmaxf(v, 0.f) + log1pf(expf(-fabsf(v)));
        cp[j] = v;
      }
    }
  }
}

// ---------------------------------------------------------------------------
// causal depthwise conv (k=4) + bias + SiLU. Reads xc = xz[:, 0:DIN].
// ---------------------------------------------------------------------------
__global__ __launch_bounds__(256) void conv_kernel(
    const float* __restrict__ xz, const float* __restrict__ cw,
    const float* __restrict__ cb, float* __restrict__ u) {
  int idx = blockIdx.x * 256 + threadIdx.x;
  int d = idx & (DIN - 1);
  int m = idx >> 10;
  int t = m & (Ldim - 1);
  float w0 = cw[d * 4 + 0], w1 = cw[d * 4 + 1], w2 = cw[d * 4 + 2],
        w3 = cw[d * 4 + 3];
  float acc = cb[d];
  if (t >= 3) acc = fmaf(xz[(size_t)(m - 3) * 2048 + d], w0, acc);
  if (t >= 2) acc = fmaf(xz[(size_t)(m - 2) * 2048 + d], w1, acc);
  if (t >= 1) acc = fmaf(xz[(size_t)(m - 1) * 2048 + d], w2, acc);
  acc = fmaf(xz[(size_t)m * 2048 + d], w3, acc);
  u[(size_t)m * DIN + d] = acc / (1.f + __expf(-acc));
}

// ---------------------------------------------------------------------------
// Chunked selective scan pass 1
// ---------------------------------------------------------------------------
__global__ __launch_bounds__(256) void scan1_kernel(
    const float* __restrict__ xz, const float* __restrict__ u,
    const float* __restrict__ dbl, const float* __restrict__ A_log,
    float* __restrict__ Hsum, float* __restrict__ Aprod) {
  __shared__ float Bsh[CHUNK][NST];
  int tid = threadIdx.x;
  int d = blockIdx.x * 256 + tid;
  int c = blockIdx.y;
  int b = blockIdx.z;
  size_t mbase = (size_t)b * Ldim + (size_t)c * CHUNK;
  for (int i = tid; i < CHUNK * NST; i += 256) {
    int t = i >> 4, n = i & 15;
    Bsh[t][n] = dbl[(mbase + t) * 64 + 32 + n];
  }
  float Adn[NST];
  #pragma unroll
  for (int n = 0; n < NST; ++n) Adn[n] = -__expf(A_log[d * NST + n]);
  float h[NST], ap[NST];
  #pragma unroll
  for (int n = 0; n < NST; ++n) { h[n] = 0.f; ap[n] = 1.f; }
  __syncthreads();
  for (int t = 0; t < CHUNK; ++t) {
    size_t m = mbase + t;
    float delta = xz[m * 2048 + d];
    float uv = u[m * DIN + d];
    float du = delta * uv;
    #pragma unroll
    for (int n = 0; n < NST; ++n) {
      float a = __expf(delta * Adn[n]);
      h[n] = fmaf(a, h[n], du * Bsh[t][n]);
      ap[n] *= a;
    }
  }
  size_t base = ((size_t)(b * NCHUNK + c) * NST) * DIN + d;
  #pragma unroll
  for (int n = 0; n < NST; ++n) {
    Hsum[base + (size_t)n * DIN] = h[n];
    Aprod[base + (size_t)n * DIN] = ap[n];
  }
}

// ---------------------------------------------------------------------------
// pass 2: serial carry over the 16 chunks -> exclusive chunk-start state
// ---------------------------------------------------------------------------
__global__ __launch_bounds__(256) void scan2_kernel(
    float* __restrict__ Hsum, const float* __restrict__ Aprod) {
  int idx = blockIdx.x * 256 + threadIdx.x;
  int d = idx & (DIN - 1);
  int bn = idx >> 10;
  int n = bn & 15;
  int b = bn >> 4;
  float carry = 0.f;
  for (int c = 0; c < NCHUNK; ++c) {
    size_t off = ((size_t)((b * NCHUNK + c) * NST + n)) * DIN + d;
    float hs = Hsum[off];
    float apv = Aprod[off];
    Hsum[off] = carry;
    carry = fmaf(apv, carry, hs);
  }
}

// ---------------------------------------------------------------------------
// pass 3: replay with carry, y = C·h + u*Dp, gate silu(z); y overwrites u
// ---------------------------------------------------------------------------
__global__ __launch_bounds__(256) void scan3_kernel(
    const float* __restrict__ xz, float* __restrict__ u,
    const float* __restrict__ dbl, const float* __restrict__ A_log,
    const float* __restrict__ Dp, const float* __restrict__ Hstart) {
  __shared__ float Bsh[CHUNK][NST];
  __shared__ float Csh[CHUNK][NST];
  int tid = threadIdx.x;
  int d = blockIdx.x * 256 + tid;
  int c = blockIdx.y;
  int b = blockIdx.z;
  size_t mbase = (size_t)b * Ldim + (size_t)c * CHUNK;
  for (int i = tid; i < CHUNK * NST; i += 256) {
    int t = i >> 4, n = i & 15;
    Bsh[t][n] = dbl[(mbase + t) * 64 + 32 + n];
    Csh[t][n] = dbl[(mbase + t) * 64 + 48 + n];
  }
  float Adn[NST];
  #pragma unroll
  for (int n = 0; n < NST; ++n) Adn[n] = -__expf(A_log[d * NST + n]);
  float h[NST];
  size_t base = ((size_t)(b * NCHUNK + c) * NST) * DIN + d;
  #pragma unroll
  for (int n = 0; n < NST; ++n) h[n] = Hstart[base + (size_t)n * DIN];
  float Dpd = Dp[d];
  __syncthreads();
  for (int t = 0; t < CHUNK; ++t) {
    size_t m = mbase + t;
    float delta = xz[m * 2048 + d];
    float uv = u[m * DIN + d];
    float du = delta * uv;
    float y = 0.f;
    #pragma unroll
    for (int n = 0; n < NST; ++n) {
      float a = __expf(delta * Adn[n]);
      h[n] = fmaf(a, h[n], du * Bsh[t][n]);
      y = fmaf(h[n], Csh[t][n], y);
    }
    float z = xz[m * 2048 + DIN + d];
    float sz = z / (1.f + __expf(-z));
    u[m * DIN + d] = (y + uv * Dpd) * sz;
  }
}

// ---------------------------------------------------------------------------
// maxpool over time + fc
// ---------------------------------------------------------------------------
__global__ __launch_bounds__(256) void pool1_kernel(
    const float* __restrict__ h, float* __restrict__ pm) {
  int b = blockIdx.x, r = blockIdx.y;
  int tid = threadIdx.x;
  #pragma unroll
  for (int rep = 0; rep < 2; ++rep) {
    int j = tid + rep * 256;
    float mx = -1e30f;
    size_t base = ((size_t)b * Ldim + r * 128) * Hdim + j;
    for (int t = 0; t < 128; ++t) mx = fmaxf(mx, h[base + (size_t)t * Hdim]);
    pm[((size_t)b * 8 + r) * Hdim + j] = mx;
  }
}

__global__ __launch_bounds__(256) void pool2_kernel(
    const float* __restrict__ pm, const float* __restrict__ fcw,
    const float* __restrict__ fcb, float* __restrict__ out) {
  int b = blockIdx.x, tid = threadIdx.x;
  float acc = 0.f;
  #pragma unroll
  for (int rep = 0; rep < 2; ++rep) {
    int j = tid + rep * 256;
    float mx = -1e30f;
    for (int r = 0; r < 8; ++r) mx = fmaxf(mx, pm[((size_t)b * 8 + r) * Hdim + j]);
    acc += mx * fcw[j];
  }
  __shared__ float red[256];
  red[tid] = acc;
  __syncthreads();
  for (int s = 128; s > 0; s >>= 1) {
    if (tid < s) red[tid] += red[tid + s];
    __syncthreads();
  }
  if (tid == 0) out[b] = red[0] + fcb[0];
}

// ---------------------------------------------------------------------------
extern "C" void kernel_launch(void* const* d_in, const int* in_sizes, int n_in,
                              void* d_out, int out_size, void* d_ws,
                              size_t ws_size, hipStream_t stream) {
  const float* x         = (const float*)d_in[0];
  const float* ln_g      = (const float*)d_in[1];
  const float* ln_b      = (const float*)d_in[2];
  const float* proj_w    = (const float*)d_in[3];
  const float* proj_b    = (const float*)d_in[4];
  const float* in_proj_w = (const float*)d_in[5];
  const float* conv_w    = (const float*)d_in[6];
  const float* conv_b    = (const float*)d_in[7];
  const float* xproj_w   = (const float*)d_in[8];
  const float* dtproj_w  = (const float*)d_in[9];
  const float* dtproj_b  = (const float*)d_in[10];
  const float* A_log     = (const float*)d_in[11];
  const float* Dp        = (const float*)d_in[12];
  const float* out_pw    = (const float*)d_in[13];
  const float* fc_w      = (const float*)d_in[14];
  const float* fc_b      = (const float*)d_in[15];
  float* out = (float*)d_out;

  float* ws   = (float*)d_ws;
  float* xl   = ws;                                 // M*64
  float* hbuf = xl + (size_t)Mrows * Pdim;          // M*512
  float* xz   = hbuf + (size_t)Mrows * Hdim;        // M*2048
  float* ubuf = xz + (size_t)Mrows * 2 * DIN;       // M*1024
  float* dbl  = ubuf + (size_t)Mrows * DIN;         // M*64
  float* pm   = dbl + (size_t)Mrows * 64;           // 8*8*512
  // scan scratch overlays hbuf (dead between in_proj and out_proj)
  float* Hsum  = hbuf;
  float* Aprod = hbuf + (size_t)Bdim * NCHUNK * NST * DIN;
  // bf16-split buffers overlay dead regions:
  // in_proj: A' (M x 3*512 bf16 = 6,291,456 fl) + W' (2048 x 1536 bf16) in ubuf
  short* Abin = (short*)ubuf;
  short* Wbin = (short*)(ubuf + (size_t)6291456);
  // out_proj: A' (M x 3*1024 bf16 = 12,582,912 fl) + W' (512 x 3072) in xz
  short* About = (short*)xz;
  short* Wbout = (short*)(xz + (size_t)12582912);

  // LN + input projection: h = LN(x) @ proj_w^T + proj_b
  ln_kernel<<<Mrows / 4, 256, 0, stream>>>(x, ln_g, ln_b, xl);
  gemm_kernel<<<dim3(Hdim / BN, Mrows / BM), 256, 0, stream>>>(
      xl, Pdim, proj_w, hbuf, Hdim, Hdim, Pdim, proj_b, 0);

  for (int l = 0; l < NLdim; ++l) {
    const float* w_in = in_proj_w + (size_t)l * 2 * DIN * Hdim;
    const float* cw   = conv_w + (size_t)l * DIN * 4;
    const float* cb   = conv_b + (size_t)l * DIN;
    const float* w_x  = xproj_w + (size_t)l * 64 * DIN;
    const float* w_dt = dtproj_w + (size_t)l * DIN * DTR;
    const float* b_dt = dtproj_b + (size_t)l * DIN;
    const float* Al   = A_log + (size_t)l * DIN * NST;
    const float* Dl   = Dp + (size_t)l * DIN;
    const float* w_o  = out_pw + (size_t)l * Hdim * DIN;

    // xz = h @ w_in^T via split-bf16 MFMA (K'=1536)
    split_bf16_kernel<<<Mrows * Hdim / 512, 256, 0, stream>>>(hbuf, Abin, 9, 0);
    split_bf16_kernel<<<2 * DIN * Hdim / 512, 256, 0, stream>>>(w_in, Wbin, 9, 1);
    gemm_mfma<<<dim3(2 * DIN / 128, Mrows / 128), 256, 0, stream>>>(
        Abin, Wbin, xz, 3 * Hdim, 2 * DIN);
    // u = silu(causal_conv(xc) + cb)
    conv_kernel<<<(size_t)Mrows * DIN / 256, 256, 0, stream>>>(xz, cw, cb, ubuf);
    // dbl = u @ w_x^T   (M,64)
    gemm_kernel<<<dim3(1, Mrows / BM), 256, 0, stream>>>(
        ubuf, DIN, w_x, dbl, 64, 64, DIN, nullptr, 0);
    // delta = softplus(dt @ w_dt^T + b_dt) -> xz[:, 0:1024]
    gemm_kernel<<<dim3(DIN / BN, Mrows / BM), 256, 0, stream>>>(
        dbl, 64, w_dt, xz, 2 * DIN, DIN, DTR, b_dt, 1);
    // chunked selective scan
    scan1_kernel<<<dim3(DIN / 256, NCHUNK, Bdim), 256, 0, stream>>>(
        xz, ubuf, dbl, Al, Hsum, Aprod);
    scan2_kernel<<<Bdim * NST * DIN / 256, 256, 0, stream>>>(Hsum, Aprod);
    scan3_kernel<<<dim3(DIN / 256, NCHUNK, Bdim), 256, 0, stream>>>(
        xz, ubuf, dbl, Al, Dl, Hsum);
    // h = y @ w_out^T via split-bf16 MFMA (K'=3072)
    split_bf16_kernel<<<Mrows * DIN / 512, 256, 0, stream>>>(ubuf, About, 10, 0);
    split_bf16_kernel<<<Hdim * DIN / 512, 256, 0, stream>>>(w_o, Wbout, 10, 1);
    gemm_mfma<<<dim3(Hdim / 128, Mrows / 128), 256, 0, stream>>>(
        About, Wbout, hbuf, 3 * DIN, Hdim);
  }

  pool1_kernel<<<dim3(Bdim, 8), 256, 0, stream>>>(hbuf, pm);
  pool2_kernel<<<Bdim, 256, 0, stream>>>(pm, fc_w, fc_b, out);
}

// Round 4
// 1684.783 us; speedup vs baseline: 3.3527x; 1.2165x over previous
//
#include <hip/hip_runtime.h>
#include <math.h>

#define Bdim 8
#define Ldim 1024
#define Pdim 64
#define Hdim 512
#define NLdim 4
#define DIN 1024
#define NST 16
#define DTR 32
#define Mrows (Bdim * Ldim)   // 8192
#define CHUNK 64
#define NCHUNK (Ldim / CHUNK) // 16

typedef unsigned int u32;
typedef __attribute__((ext_vector_type(8))) short bf16x8;
typedef __attribute__((ext_vector_type(4))) float f32x4;

__device__ __forceinline__ short f2bf(float f) {
  union { float f; u32 u; } v; v.f = f;
  u32 r = v.u + 0x7fffu + ((v.u >> 16) & 1u);
  return (short)(r >> 16);
}
__device__ __forceinline__ float bf2f(short h) {
  union { u32 u; float f; } v; v.u = ((u32)(unsigned short)h) << 16;
  return v.f;
}
__device__ __forceinline__ void gld16(const short* g, short* l) {
  __builtin_amdgcn_global_load_lds(
      (const __attribute__((address_space(1))) void*)g,
      (__attribute__((address_space(3))) void*)l, 16, 0, 0);
}

// ---------------------------------------------------------------------------
// minmax-normalize + LayerNorm, one wave per row of 64 elements
// ---------------------------------------------------------------------------
__global__ __launch_bounds__(256) void ln_kernel(
    const float* __restrict__ x, const float* __restrict__ g,
    const float* __restrict__ bta, float* __restrict__ xl) {
  int row = blockIdx.x * 4 + (threadIdx.x >> 6);
  int lane = threadIdx.x & 63;
  float v = x[(size_t)row * Pdim + lane];
  float mn = v, mx = v;
  #pragma unroll
  for (int m = 1; m < 64; m <<= 1) {
    mn = fminf(mn, __shfl_xor(mn, m, 64));
    mx = fmaxf(mx, __shfl_xor(mx, m, 64));
  }
  float xn = (v - mn) / (mx - mn + 1e-6f);
  float s = xn, s2 = xn * xn;
  #pragma unroll
  for (int m = 1; m < 64; m <<= 1) {
    s += __shfl_xor(s, m, 64);
    s2 += __shfl_xor(s2, m, 64);
  }
  float mu = s * (1.f / 64.f);
  float var = s2 * (1.f / 64.f) - mu * mu;
  float out = (xn - mu) * rsqrtf(var + 1e-5f) * g[lane] + bta[lane];
  xl[(size_t)row * Pdim + lane] = out;
}

// ---------------------------------------------------------------------------
// split fp32 -> concatenated bf16 triple. wstyle=0: [hi|lo|hi], 1: [hi|hi|lo]
// ---------------------------------------------------------------------------
__global__ __launch_bounds__(256) void split_bf16_kernel(
    const float* __restrict__ X, short* __restrict__ Xb, int kshift,
    int wstyle) {
  int idx = blockIdx.x * 256 + threadIdx.x;
  int K = 1 << kshift;
  int m = idx >> (kshift - 1);
  int k2 = (idx & ((K >> 1) - 1)) << 1;
  float2 v = *(const float2*)&X[((size_t)m << kshift) + k2];
  short h0 = f2bf(v.x), h1 = f2bf(v.y);
  short l0 = f2bf(v.x - bf2f(h0)), l1 = f2bf(v.y - bf2f(h1));
  short2 hh; hh.x = h0; hh.y = h1;
  short2 ll; ll.x = l0; ll.y = l1;
  size_t base = (size_t)m * 3 * K + k2;
  *(short2*)&Xb[base] = hh;
  *(short2*)&Xb[base + K] = wstyle ? hh : ll;
  *(short2*)&Xb[base + 2 * K] = wstyle ? ll : hh;
}

// ---------------------------------------------------------------------------
// bf16 MFMA GEMM (m97 structure): C(M,Nx) = Ab(M,Kp) * Wb(Nx,Kp)^T, fp32 out.
// ---------------------------------------------------------------------------
__global__ __launch_bounds__(256) void gemm_mfma(
    const short* __restrict__ Ab, const short* __restrict__ Wb,
    float* __restrict__ C, int Kp, int ldc) {
  __shared__ short As[128 * 32];
  __shared__ short Bs[128 * 32];
  int tid = threadIdx.x;
  int lane = tid & 63;
  int wave = tid >> 6;
  int quad = lane >> 4, l16 = lane & 15;
  int wm = (wave & 1) * 64, wn = (wave >> 1) * 64;
  int row0 = blockIdx.y * 128, col0 = blockIdx.x * 128;

  f32x4 acc[4][4];
  #pragma unroll
  for (int i = 0; i < 4; ++i)
    #pragma unroll
    for (int j = 0; j < 4; ++j) acc[i][j] = (f32x4){0.f, 0.f, 0.f, 0.f};

  int lin0 = tid, lin1 = tid + 256;
  const short* gA0 = Ab + (size_t)(row0 + (lin0 >> 2)) * Kp + ((lin0 & 3) << 3);
  const short* gA1 = Ab + (size_t)(row0 + (lin1 >> 2)) * Kp + ((lin1 & 3) << 3);
  const short* gB0 = Wb + (size_t)(col0 + (lin0 >> 2)) * Kp + ((lin0 & 3) << 3);
  const short* gB1 = Wb + (size_t)(col0 + (lin1 >> 2)) * Kp + ((lin1 & 3) << 3);
  short* lA0 = &As[lin0 * 8];
  short* lA1 = &As[lin1 * 8];
  short* lB0 = &Bs[lin0 * 8];
  short* lB1 = &Bs[lin1 * 8];

  for (int k0 = 0; k0 < Kp; k0 += 32) {
    __syncthreads();
    gld16(gA0 + k0, lA0);
    gld16(gA1 + k0, lA1);
    gld16(gB0 + k0, lB0);
    gld16(gB1 + k0, lB1);
    __syncthreads();
    bf16x8 af[4], bfr[4];
    #pragma unroll
    for (int t = 0; t < 4; ++t) {
      af[t]  = *(const bf16x8*)&As[(wm + t * 16 + l16) * 32 + quad * 8];
      bfr[t] = *(const bf16x8*)&Bs[(wn + t * 16 + l16) * 32 + quad * 8];
    }
    #pragma unroll
    for (int tm = 0; tm < 4; ++tm)
      #pragma unroll
      for (int tn = 0; tn < 4; ++tn)
        acc[tm][tn] = __builtin_amdgcn_mfma_f32_16x16x32_bf16(
            af[tm], bfr[tn], acc[tm][tn], 0, 0, 0);
  }

  #pragma unroll
  for (int tm = 0; tm < 4; ++tm) {
    #pragma unroll
    for (int r = 0; r < 4; ++r) {
      int row = row0 + wm + tm * 16 + quad * 4 + r;
      float* cp = C + (size_t)row * ldc + col0 + wn + l16;
      #pragma unroll
      for (int tn = 0; tn < 4; ++tn) cp[tn * 16] = acc[tm][tn][r];
    }
  }
}

// ---------------------------------------------------------------------------
// Generic fp32 GEMM (now only used for the first projection, K=64)
// ---------------------------------------------------------------------------
#define BM 128
#define BN 128
#define BK 16

__global__ __launch_bounds__(256) void gemm_kernel(
    const float* __restrict__ A, int lda, const float* __restrict__ Bw,
    float* __restrict__ C, int ldc, int Nx, int K,
    const float* __restrict__ bias, int act) {
  __shared__ float As[BK][BM];
  __shared__ float Bs[BK][BN];
  int tid = threadIdx.x;
  int tx = tid & 15, ty = tid >> 4;
  int row0 = blockIdx.y * BM;
  int col0 = blockIdx.x * BN;

  float acc[8][8];
  #pragma unroll
  for (int i = 0; i < 8; ++i)
    #pragma unroll
    for (int j = 0; j < 8; ++j) acc[i][j] = 0.f;

  int lr = tid >> 1;
  int lk = (tid & 1) * 8;

  for (int k0 = 0; k0 < K; k0 += BK) {
    const float* ap = A + (size_t)(row0 + lr) * lda + (k0 + lk);
    float4 a0 = *(const float4*)ap;
    float4 a1 = *(const float4*)(ap + 4);
    int bn = col0 + lr;
    float4 b0 = make_float4(0.f, 0.f, 0.f, 0.f);
    float4 b1 = make_float4(0.f, 0.f, 0.f, 0.f);
    if (bn < Nx) {
      const float* bp = Bw + (size_t)bn * K + (k0 + lk);
      b0 = *(const float4*)bp;
      b1 = *(const float4*)(bp + 4);
    }
    __syncthreads();
    As[lk + 0][lr] = a0.x; As[lk + 1][lr] = a0.y;
    As[lk + 2][lr] = a0.z; As[lk + 3][lr] = a0.w;
    As[lk + 4][lr] = a1.x; As[lk + 5][lr] = a1.y;
    As[lk + 6][lr] = a1.z; As[lk + 7][lr] = a1.w;
    Bs[lk + 0][lr] = b0.x; Bs[lk + 1][lr] = b0.y;
    Bs[lk + 2][lr] = b0.z; Bs[lk + 3][lr] = b0.w;
    Bs[lk + 4][lr] = b1.x; Bs[lk + 5][lr] = b1.y;
    Bs[lk + 6][lr] = b1.z; Bs[lk + 7][lr] = b1.w;
    __syncthreads();
    #pragma unroll
    for (int kk = 0; kk < BK; ++kk) {
      float af[8], bf[8];
      *(float4*)(af)     = *(const float4*)(&As[kk][ty * 8]);
      *(float4*)(af + 4) = *(const float4*)(&As[kk][ty * 8 + 4]);
      *(float4*)(bf)     = *(const float4*)(&Bs[kk][tx * 8]);
      *(float4*)(bf + 4) = *(const float4*)(&Bs[kk][tx * 8 + 4]);
      #pragma unroll
      for (int i = 0; i < 8; ++i)
        #pragma unroll
        for (int j = 0; j < 8; ++j)
          acc[i][j] = fmaf(af[i], bf[j], acc[i][j]);
    }
  }
  __syncthreads();

  #pragma unroll
  for (int i = 0; i < 8; ++i) {
    int r = row0 + ty * 8 + i;
    float* cp = C + (size_t)r * ldc + col0 + tx * 8;
    #pragma unroll
    for (int j = 0; j < 8; ++j) {
      int c = col0 + tx * 8 + j;
      if (c < Nx) {
        float v = acc[i][j];
        if (bias) v += bias[c];
        if (act == 1) v = fmaxf(v, 0.f) + log1pf(expf(-fabsf(v)));
        cp[j] = v;
      }
    }
  }
}

// ---------------------------------------------------------------------------
// x_proj specialized: dbl(M,64) = u(M,1024) @ w_x(64,1024)^T
// 32 rows/block -> 256 blocks. LDS tiles k-major, padded (+1) vs bank stride.
// microtile 2 rows x 4 cols per thread.
// ---------------------------------------------------------------------------
#define XBK 64
__global__ __launch_bounds__(256) void xproj_kernel(
    const float* __restrict__ u, const float* __restrict__ wx,
    float* __restrict__ dbl) {
  __shared__ float As[XBK][33];   // [k][row]
  __shared__ float Bs[XBK][65];   // [k][j]
  int tid = threadIdx.x;
  int m0 = blockIdx.x * 32;
  int ty = tid >> 4;        // 0..15 -> rows ty*2, ty*2+1
  int tx = tid & 15;        // 0..15 -> cols tx*4..tx*4+3
  float acc[2][4];
  #pragma unroll
  for (int i = 0; i < 2; ++i)
    #pragma unroll
    for (int j = 0; j < 4; ++j) acc[i][j] = 0.f;

  for (int k0 = 0; k0 < DIN; k0 += XBK) {
    __syncthreads();
    // stage A: 32 rows x 64 k = 512 float4, 2 per thread
    #pragma unroll
    for (int rep = 0; rep < 2; ++rep) {
      int f = tid * 2 + rep;
      int row = f >> 4;
      int kk = (f & 15) << 2;
      float4 v = *(const float4*)&u[(size_t)(m0 + row) * DIN + k0 + kk];
      As[kk + 0][row] = v.x; As[kk + 1][row] = v.y;
      As[kk + 2][row] = v.z; As[kk + 3][row] = v.w;
    }
    // stage B: 64 j x 64 k = 1024 float4, 4 per thread
    #pragma unroll
    for (int rep = 0; rep < 4; ++rep) {
      int f = tid * 4 + rep;
      int j = f >> 4;
      int kk = (f & 15) << 2;
      float4 v = *(const float4*)&wx[(size_t)j * DIN + k0 + kk];
      Bs[kk + 0][j] = v.x; Bs[kk + 1][j] = v.y;
      Bs[kk + 2][j] = v.z; Bs[kk + 3][j] = v.w;
    }
    __syncthreads();
    #pragma unroll 8
    for (int kk = 0; kk < XBK; ++kk) {
      float af0 = As[kk][ty * 2], af1 = As[kk][ty * 2 + 1];
      float bf[4];
      *(float4*)bf = *(const float4*)&Bs[kk][tx * 4];
      #pragma unroll
      for (int j = 0; j < 4; ++j) {
        acc[0][j] = fmaf(af0, bf[j], acc[0][j]);
        acc[1][j] = fmaf(af1, bf[j], acc[1][j]);
      }
    }
  }
  #pragma unroll
  for (int i = 0; i < 2; ++i) {
    float4 v = make_float4(acc[i][0], acc[i][1], acc[i][2], acc[i][3]);
    *(float4*)&dbl[(size_t)(m0 + ty * 2 + i) * 64 + tx * 4] = v;
  }
}

// ---------------------------------------------------------------------------
// dt_proj specialized: delta(M,1024) = softplus(dbl[:,0:32] @ w_dt^T + b_dt)
// written into xz[:, 0:1024] (stride 2048). 8 rows x 256 cols per block.
// w_dt row in registers; dbl rows broadcast from LDS.
// ---------------------------------------------------------------------------
__global__ __launch_bounds__(256) void dtproj_kernel(
    const float* __restrict__ dbl, const float* __restrict__ wdt,
    const float* __restrict__ bdt, float* __restrict__ xz) {
  __shared__ float dsh[8][DTR];
  int tid = threadIdx.x;
  int d = blockIdx.x * 256 + tid;
  int m0 = blockIdx.y * 8;
  {
    int r = tid >> 5, k = tid & 31;
    dsh[r][k] = dbl[(size_t)(m0 + r) * 64 + k];
  }
  float w[DTR];
  #pragma unroll
  for (int q = 0; q < DTR / 4; ++q)
    *(float4*)&w[q * 4] = *(const float4*)&wdt[(size_t)d * DTR + q * 4];
  float bb = bdt[d];
  __syncthreads();
  #pragma unroll
  for (int r = 0; r < 8; ++r) {
    float s = bb;
    #pragma unroll
    for (int k = 0; k < DTR; ++k) s = fmaf(dsh[r][k], w[k], s);
    float v = fmaxf(s, 0.f) + log1pf(expf(-fabsf(s)));  // softplus
    xz[(size_t)(m0 + r) * 2048 + d] = v;
  }
}

// ---------------------------------------------------------------------------
// causal depthwise conv (k=4) + bias + SiLU. Reads xc = xz[:, 0:DIN].
// ---------------------------------------------------------------------------
__global__ __launch_bounds__(256) void conv_kernel(
    const float* __restrict__ xz, const float* __restrict__ cw,
    const float* __restrict__ cb, float* __restrict__ u) {
  int idx = blockIdx.x * 256 + threadIdx.x;
  int d = idx & (DIN - 1);
  int m = idx >> 10;
  int t = m & (Ldim - 1);
  float w0 = cw[d * 4 + 0], w1 = cw[d * 4 + 1], w2 = cw[d * 4 + 2],
        w3 = cw[d * 4 + 3];
  float acc = cb[d];
  if (t >= 3) acc = fmaf(xz[(size_t)(m - 3) * 2048 + d], w0, acc);
  if (t >= 2) acc = fmaf(xz[(size_t)(m - 2) * 2048 + d], w1, acc);
  if (t >= 1) acc = fmaf(xz[(size_t)(m - 1) * 2048 + d], w2, acc);
  acc = fmaf(xz[(size_t)m * 2048 + d], w3, acc);
  u[(size_t)m * DIN + d] = acc / (1.f + __expf(-acc));
}

// ---------------------------------------------------------------------------
// Chunked selective scan pass 1
// ---------------------------------------------------------------------------
__global__ __launch_bounds__(256) void scan1_kernel(
    const float* __restrict__ xz, const float* __restrict__ u,
    const float* __restrict__ dbl, const float* __restrict__ A_log,
    float* __restrict__ Hsum, float* __restrict__ Aprod) {
  __shared__ float Bsh[CHUNK][NST];
  int tid = threadIdx.x;
  int d = blockIdx.x * 256 + tid;
  int c = blockIdx.y;
  int b = blockIdx.z;
  size_t mbase = (size_t)b * Ldim + (size_t)c * CHUNK;
  for (int i = tid; i < CHUNK * NST; i += 256) {
    int t = i >> 4, n = i & 15;
    Bsh[t][n] = dbl[(mbase + t) * 64 + 32 + n];
  }
  float Adn[NST];
  #pragma unroll
  for (int n = 0; n < NST; ++n) Adn[n] = -__expf(A_log[d * NST + n]);
  float h[NST], ap[NST];
  #pragma unroll
  for (int n = 0; n < NST; ++n) { h[n] = 0.f; ap[n] = 1.f; }
  __syncthreads();
  for (int t = 0; t < CHUNK; ++t) {
    size_t m = mbase + t;
    float delta = xz[m * 2048 + d];
    float uv = u[m * DIN + d];
    float du = delta * uv;
    #pragma unroll
    for (int n = 0; n < NST; ++n) {
      float a = __expf(delta * Adn[n]);
      h[n] = fmaf(a, h[n], du * Bsh[t][n]);
      ap[n] *= a;
    }
  }
  size_t base = ((size_t)(b * NCHUNK + c) * NST) * DIN + d;
  #pragma unroll
  for (int n = 0; n < NST; ++n) {
    Hsum[base + (size_t)n * DIN] = h[n];
    Aprod[base + (size_t)n * DIN] = ap[n];
  }
}

// ---------------------------------------------------------------------------
// pass 2: serial carry over the 16 chunks -> exclusive chunk-start state
// ---------------------------------------------------------------------------
__global__ __launch_bounds__(256) void scan2_kernel(
    float* __restrict__ Hsum, const float* __restrict__ Aprod) {
  int idx = blockIdx.x * 256 + threadIdx.x;
  int d = idx & (DIN - 1);
  int bn = idx >> 10;
  int n = bn & 15;
  int b = bn >> 4;
  float carry = 0.f;
  for (int c = 0; c < NCHUNK; ++c) {
    size_t off = ((size_t)((b * NCHUNK + c) * NST + n)) * DIN + d;
    float hs = Hsum[off];
    float apv = Aprod[off];
    Hsum[off] = carry;
    carry = fmaf(apv, carry, hs);
  }
}

// ---------------------------------------------------------------------------
// pass 3: replay with carry, y = C·h + u*Dp, gate silu(z); y overwrites u
// ---------------------------------------------------------------------------
__global__ __launch_bounds__(256) void scan3_kernel(
    const float* __restrict__ xz, float* __restrict__ u,
    const float* __restrict__ dbl, const float* __restrict__ A_log,
    const float* __restrict__ Dp, const float* __restrict__ Hstart) {
  __shared__ float Bsh[CHUNK][NST];
  __shared__ float Csh[CHUNK][NST];
  int tid = threadIdx.x;
  int d = blockIdx.x * 256 + tid;
  int c = blockIdx.y;
  int b = blockIdx.z;
  size_t mbase = (size_t)b * Ldim + (size_t)c * CHUNK;
  for (int i = tid; i < CHUNK * NST; i += 256) {
    int t = i >> 4, n = i & 15;
    Bsh[t][n] = dbl[(mbase + t) * 64 + 32 + n];
    Csh[t][n] = dbl[(mbase + t) * 64 + 48 + n];
  }
  float Adn[NST];
  #pragma unroll
  for (int n = 0; n < NST; ++n) Adn[n] = -__expf(A_log[d * NST + n]);
  float h[NST];
  size_t base = ((size_t)(b * NCHUNK + c) * NST) * DIN + d;
  #pragma unroll
  for (int n = 0; n < NST; ++n) h[n] = Hstart[base + (size_t)n * DIN];
  float Dpd = Dp[d];
  __syncthreads();
  for (int t = 0; t < CHUNK; ++t) {
    size_t m = mbase + t;
    float delta = xz[m * 2048 + d];
    float uv = u[m * DIN + d];
    float du = delta * uv;
    float y = 0.f;
    #pragma unroll
    for (int n = 0; n < NST; ++n) {
      float a = __expf(delta * Adn[n]);
      h[n] = fmaf(a, h[n], du * Bsh[t][n]);
      y = fmaf(h[n], Csh[t][n], y);
    }
    float z = xz[m * 2048 + DIN + d];
    float sz = z / (1.f + __expf(-z));
    u[m * DIN + d] = (y + uv * Dpd) * sz;
  }
}

// ---------------------------------------------------------------------------
// maxpool over time + fc
// ---------------------------------------------------------------------------
__global__ __launch_bounds__(256) void pool1_kernel(
    const float* __restrict__ h, float* __restrict__ pm) {
  int b = blockIdx.x, r = blockIdx.y;
  int tid = threadIdx.x;
  #pragma unroll
  for (int rep = 0; rep < 2; ++rep) {
    int j = tid + rep * 256;
    float mx = -1e30f;
    size_t base = ((size_t)b * Ldim + r * 128) * Hdim + j;
    for (int t = 0; t < 128; ++t) mx = fmaxf(mx, h[base + (size_t)t * Hdim]);
    pm[((size_t)b * 8 + r) * Hdim + j] = mx;
  }
}

__global__ __launch_bounds__(256) void pool2_kernel(
    const float* __restrict__ pm, const float* __restrict__ fcw,
    const float* __restrict__ fcb, float* __restrict__ out) {
  int b = blockIdx.x, tid = threadIdx.x;
  float acc = 0.f;
  #pragma unroll
  for (int rep = 0; rep < 2; ++rep) {
    int j = tid + rep * 256;
    float mx = -1e30f;
    for (int r = 0; r < 8; ++r) mx = fmaxf(mx, pm[((size_t)b * 8 + r) * Hdim + j]);
    acc += mx * fcw[j];
  }
  __shared__ float red[256];
  red[tid] = acc;
  __syncthreads();
  for (int s = 128; s > 0; s >>= 1) {
    if (tid < s) red[tid] += red[tid + s];
    __syncthreads();
  }
  if (tid == 0) out[b] = red[0] + fcb[0];
}

// ---------------------------------------------------------------------------
extern "C" void kernel_launch(void* const* d_in, const int* in_sizes, int n_in,
                              void* d_out, int out_size, void* d_ws,
                              size_t ws_size, hipStream_t stream) {
  const float* x         = (const float*)d_in[0];
  const float* ln_g      = (const float*)d_in[1];
  const float* ln_b      = (const float*)d_in[2];
  const float* proj_w    = (const float*)d_in[3];
  const float* proj_b    = (const float*)d_in[4];
  const float* in_proj_w = (const float*)d_in[5];
  const float* conv_w    = (const float*)d_in[6];
  const float* conv_b    = (const float*)d_in[7];
  const float* xproj_w   = (const float*)d_in[8];
  const float* dtproj_w  = (const float*)d_in[9];
  const float* dtproj_b  = (const float*)d_in[10];
  const float* A_log     = (const float*)d_in[11];
  const float* Dp        = (const float*)d_in[12];
  const float* out_pw    = (const float*)d_in[13];
  const float* fc_w      = (const float*)d_in[14];
  const float* fc_b      = (const float*)d_in[15];
  float* out = (float*)d_out;

  float* ws   = (float*)d_ws;
  float* xl   = ws;                                 // M*64
  float* hbuf = xl + (size_t)Mrows * Pdim;          // M*512
  float* xz   = hbuf + (size_t)Mrows * Hdim;        // M*2048
  float* ubuf = xz + (size_t)Mrows * 2 * DIN;       // M*1024
  float* dbl  = ubuf + (size_t)Mrows * DIN;         // M*64
  float* pm   = dbl + (size_t)Mrows * 64;           // 8*8*512
  float* Hsum  = hbuf;
  float* Aprod = hbuf + (size_t)Bdim * NCHUNK * NST * DIN;
  short* Abin = (short*)ubuf;
  short* Wbin = (short*)(ubuf + (size_t)6291456);
  short* About = (short*)xz;
  short* Wbout = (short*)(xz + (size_t)12582912);

  ln_kernel<<<Mrows / 4, 256, 0, stream>>>(x, ln_g, ln_b, xl);
  gemm_kernel<<<dim3(Hdim / BN, Mrows / BM), 256, 0, stream>>>(
      xl, Pdim, proj_w, hbuf, Hdim, Hdim, Pdim, proj_b, 0);

  for (int l = 0; l < NLdim; ++l) {
    const float* w_in = in_proj_w + (size_t)l * 2 * DIN * Hdim;
    const float* cw   = conv_w + (size_t)l * DIN * 4;
    const float* cb   = conv_b + (size_t)l * DIN;
    const float* w_x  = xproj_w + (size_t)l * 64 * DIN;
    const float* w_dt = dtproj_w + (size_t)l * DIN * DTR;
    const float* b_dt = dtproj_b + (size_t)l * DIN;
    const float* Al   = A_log + (size_t)l * DIN * NST;
    const float* Dl   = Dp + (size_t)l * DIN;
    const float* w_o  = out_pw + (size_t)l * Hdim * DIN;

    // xz = h @ w_in^T via split-bf16 MFMA (K'=1536)
    split_bf16_kernel<<<Mrows * Hdim / 512, 256, 0, stream>>>(hbuf, Abin, 9, 0);
    split_bf16_kernel<<<2 * DIN * Hdim / 512, 256, 0, stream>>>(w_in, Wbin, 9, 1);
    gemm_mfma<<<dim3(2 * DIN / 128, Mrows / 128), 256, 0, stream>>>(
        Abin, Wbin, xz, 3 * Hdim, 2 * DIN);
    // u = silu(causal_conv(xc) + cb)
    conv_kernel<<<(size_t)Mrows * DIN / 256, 256, 0, stream>>>(xz, cw, cb, ubuf);
    // dbl = u @ w_x^T   (M,64) — specialized, 256 blocks
    xproj_kernel<<<Mrows / 32, 256, 0, stream>>>(ubuf, w_x, dbl);
    // delta = softplus(dt @ w_dt^T + b_dt) -> xz[:, 0:1024] — specialized
    dtproj_kernel<<<dim3(DIN / 256, Mrows / 8), 256, 0, stream>>>(
        dbl, w_dt, b_dt, xz);
    // chunked selective scan
    scan1_kernel<<<dim3(DIN / 256, NCHUNK, Bdim), 256, 0, stream>>>(
        xz, ubuf, dbl, Al, Hsum, Aprod);
    scan2_kernel<<<Bdim * NST * DIN / 256, 256, 0, stream>>>(Hsum, Aprod);
    scan3_kernel<<<dim3(DIN / 256, NCHUNK, Bdim), 256, 0, stream>>>(
        xz, ubuf, dbl, Al, Dl, Hsum);
    // h = y @ w_out^T via split-bf16 MFMA (K'=3072)
    split_bf16_kernel<<<Mrows * DIN / 512, 256, 0, stream>>>(ubuf, About, 10, 0);
    split_bf16_kernel<<<Hdim * DIN / 512, 256, 0, stream>>>(w_o, Wbout, 10, 1);
    gemm_mfma<<<dim3(Hdim / 128, Mrows / 128), 256, 0, stream>>>(
        About, Wbout, hbuf, 3 * DIN, Hdim);
  }

  pool1_kernel<<<dim3(Bdim, 8), 256, 0, stream>>>(hbuf, pm);
  pool2_kernel<<<Bdim, 256, 0, stream>>>(pm, fc_w, fc_b, out);
}

// Round 5
// 1518.139 us; speedup vs baseline: 3.7207x; 1.1098x over previous
//
#include <hip/hip_runtime.h>
#include <math.h>

#define Bdim 8
#define Ldim 1024
#define Pdim 64
#define Hdim 512
#define NLdim 4
#define DIN 1024
#define NST 16
#define DTR 32
#define Mrows (Bdim * Ldim)   // 8192
#define CHUNK 64
#define NCHUNK (Ldim / CHUNK) // 16

typedef unsigned int u32;
typedef __attribute__((ext_vector_type(8))) short bf16x8;
typedef __attribute__((ext_vector_type(4))) float f32x4;

__device__ __forceinline__ short f2bf(float f) {
  union { float f; u32 u; } v; v.f = f;
  u32 r = v.u + 0x7fffu + ((v.u >> 16) & 1u);
  return (short)(r >> 16);
}
__device__ __forceinline__ float bf2f(short h) {
  union { u32 u; float f; } v; v.u = ((u32)(unsigned short)h) << 16;
  return v.f;
}
// fp32 -> packed [hi|lo] bf16 pair (hi in low 16 bits = element 2k in memory)
__device__ __forceinline__ u32 packpair(float x) {
  short hi = f2bf(x);
  short lo = f2bf(x - bf2f(hi));
  return (u32)(unsigned short)hi | ((u32)(unsigned short)lo << 16);
}
__device__ __forceinline__ bf16x8 pairswap(bf16x8 v) {
  union { bf16x8 v; u32 u[4]; } a, b;
  a.v = v;
  #pragma unroll
  for (int i = 0; i < 4; ++i) b.u[i] = (a.u[i] << 16) | (a.u[i] >> 16);
  return b.v;
}
__device__ __forceinline__ void gld16(const short* g, short* l) {
  __builtin_amdgcn_global_load_lds(
      (const __attribute__((address_space(1))) void*)g,
      (__attribute__((address_space(3))) void*)l, 16, 0, 0);
}

// ---------------------------------------------------------------------------
// minmax-normalize + LayerNorm, one wave per row of 64 elements
// ---------------------------------------------------------------------------
__global__ __launch_bounds__(256) void ln_kernel(
    const float* __restrict__ x, const float* __restrict__ g,
    const float* __restrict__ bta, float* __restrict__ xl) {
  int row = blockIdx.x * 4 + (threadIdx.x >> 6);
  int lane = threadIdx.x & 63;
  float v = x[(size_t)row * Pdim + lane];
  float mn = v, mx = v;
  #pragma unroll
  for (int m = 1; m < 64; m <<= 1) {
    mn = fminf(mn, __shfl_xor(mn, m, 64));
    mx = fmaxf(mx, __shfl_xor(mx, m, 64));
  }
  float xn = (v - mn) / (mx - mn + 1e-6f);
  float s = xn, s2 = xn * xn;
  #pragma unroll
  for (int m = 1; m < 64; m <<= 1) {
    s += __shfl_xor(s, m, 64);
    s2 += __shfl_xor(s2, m, 64);
  }
  float mu = s * (1.f / 64.f);
  float var = s2 * (1.f / 64.f) - mu * mu;
  float out = (xn - mu) * rsqrtf(var + 1e-5f) * g[lane] + bta[lane];
  xl[(size_t)row * Pdim + lane] = out;
}

// ---------------------------------------------------------------------------
// elementwise fp32 -> packed bf16-pair (index-preserving). n % 1024 == 0.
// ---------------------------------------------------------------------------
__global__ __launch_bounds__(256) void pair_split_kernel(
    const float* __restrict__ X, u32* __restrict__ Xp) {
  int i = (blockIdx.x * 256 + threadIdx.x) * 4;
  float4 v = *(const float4*)&X[i];
  uint4 o;
  o.x = packpair(v.x); o.y = packpair(v.y);
  o.z = packpair(v.z); o.w = packpair(v.w);
  *(uint4*)&Xp[i] = o;
}

// ---------------------------------------------------------------------------
// bf16-pair MFMA GEMM: C(M,Nx) = A(M,K fp32-as-pairs) * W(Nx,K)^T, fp32 out.
// A/W stored as interleaved [hi|lo] bf16, Kp = 2K shorts. Two MFMAs per frag
// pair (plain + pairswap) give all 4 split products (exact to ~2^-17).
// Tile 128 x TN (TN = 128 or 64), 256 threads, BK = 32 shorts (16 fp32 k).
// ---------------------------------------------------------------------------
template <int TN>
__global__ __launch_bounds__(256) void gemm_pair(
    const short* __restrict__ Ab, const short* __restrict__ Wb,
    float* __restrict__ C, int Kp, int ldc) {
  constexpr int FM = (TN == 128) ? 4 : 2;
  constexpr int FN = 4;
  __shared__ short As[128 * 32];
  __shared__ short Bs[TN * 32];
  int tid = threadIdx.x;
  int lane = tid & 63;
  int wave = tid >> 6;
  int quad = lane >> 4, l16 = lane & 15;
  int wm = (TN == 128) ? (wave & 1) * 64 : wave * 32;
  int wn = (TN == 128) ? (wave >> 1) * 64 : 0;
  int row0 = blockIdx.y * 128, col0 = blockIdx.x * TN;

  f32x4 acc[FM][FN];
  #pragma unroll
  for (int i = 0; i < FM; ++i)
    #pragma unroll
    for (int j = 0; j < FN; ++j) acc[i][j] = (f32x4){0.f, 0.f, 0.f, 0.f};

  int lin0 = tid, lin1 = tid + 256;
  const short* gA0 = Ab + (size_t)(row0 + (lin0 >> 2)) * Kp + ((lin0 & 3) << 3);
  const short* gA1 = Ab + (size_t)(row0 + (lin1 >> 2)) * Kp + ((lin1 & 3) << 3);
  const short* gB0 = Wb + (size_t)(col0 + (lin0 >> 2)) * Kp + ((lin0 & 3) << 3);
  const short* gB1 = Wb + (size_t)(col0 + (lin1 >> 2)) * Kp + ((lin1 & 3) << 3);
  short* lA0 = &As[lin0 * 8];
  short* lA1 = &As[lin1 * 8];
  short* lB0 = &Bs[lin0 * 8];
  short* lB1 = &Bs[lin1 * 8];

  for (int k0 = 0; k0 < Kp; k0 += 32) {
    __syncthreads();
    gld16(gA0 + k0, lA0);
    gld16(gA1 + k0, lA1);
    gld16(gB0 + k0, lB0);
    if (TN == 128) gld16(gB1 + k0, lB1);
    __syncthreads();
    bf16x8 af[FM], afs[FM], wf[FN];
    #pragma unroll
    for (int t = 0; t < FM; ++t) {
      af[t] = *(const bf16x8*)&As[(wm + t * 16 + l16) * 32 + quad * 8];
      afs[t] = pairswap(af[t]);
    }
    #pragma unroll
    for (int t = 0; t < FN; ++t)
      wf[t] = *(const bf16x8*)&Bs[(wn + t * 16 + l16) * 32 + quad * 8];
    #pragma unroll
    for (int tm = 0; tm < FM; ++tm)
      #pragma unroll
      for (int tn = 0; tn < FN; ++tn) {
        acc[tm][tn] = __builtin_amdgcn_mfma_f32_16x16x32_bf16(
            af[tm], wf[tn], acc[tm][tn], 0, 0, 0);
        acc[tm][tn] = __builtin_amdgcn_mfma_f32_16x16x32_bf16(
            afs[tm], wf[tn], acc[tm][tn], 0, 0, 0);
      }
  }

  #pragma unroll
  for (int tm = 0; tm < FM; ++tm) {
    #pragma unroll
    for (int r = 0; r < 4; ++r) {
      int row = row0 + wm + tm * 16 + quad * 4 + r;
      float* cp = C + (size_t)row * ldc + col0 + wn + l16;
      #pragma unroll
      for (int tn = 0; tn < FN; ++tn) cp[tn * 16] = acc[tm][tn][r];
    }
  }
}

// ---------------------------------------------------------------------------
// Generic fp32 GEMM (only the first projection, K=64)
// ---------------------------------------------------------------------------
#define BM 128
#define BN 128
#define BK 16

__global__ __launch_bounds__(256) void gemm_kernel(
    const float* __restrict__ A, int lda, const float* __restrict__ Bw,
    float* __restrict__ C, int ldc, int Nx, int K,
    const float* __restrict__ bias, int act) {
  __shared__ float As[BK][BM];
  __shared__ float Bs[BK][BN];
  int tid = threadIdx.x;
  int tx = tid & 15, ty = tid >> 4;
  int row0 = blockIdx.y * BM;
  int col0 = blockIdx.x * BN;

  float acc[8][8];
  #pragma unroll
  for (int i = 0; i < 8; ++i)
    #pragma unroll
    for (int j = 0; j < 8; ++j) acc[i][j] = 0.f;

  int lr = tid >> 1;
  int lk = (tid & 1) * 8;

  for (int k0 = 0; k0 < K; k0 += BK) {
    const float* ap = A + (size_t)(row0 + lr) * lda + (k0 + lk);
    float4 a0 = *(const float4*)ap;
    float4 a1 = *(const float4*)(ap + 4);
    int bn = col0 + lr;
    float4 b0 = make_float4(0.f, 0.f, 0.f, 0.f);
    float4 b1 = make_float4(0.f, 0.f, 0.f, 0.f);
    if (bn < Nx) {
      const float* bp = Bw + (size_t)bn * K + (k0 + lk);
      b0 = *(const float4*)bp;
      b1 = *(const float4*)(bp + 4);
    }
    __syncthreads();
    As[lk + 0][lr] = a0.x; As[lk + 1][lr] = a0.y;
    As[lk + 2][lr] = a0.z; As[lk + 3][lr] = a0.w;
    As[lk + 4][lr] = a1.x; As[lk + 5][lr] = a1.y;
    As[lk + 6][lr] = a1.z; As[lk + 7][lr] = a1.w;
    Bs[lk + 0][lr] = b0.x; Bs[lk + 1][lr] = b0.y;
    Bs[lk + 2][lr] = b0.z; Bs[lk + 3][lr] = b0.w;
    Bs[lk + 4][lr] = b1.x; Bs[lk + 5][lr] = b1.y;
    Bs[lk + 6][lr] = b1.z; Bs[lk + 7][lr] = b1.w;
    __syncthreads();
    #pragma unroll
    for (int kk = 0; kk < BK; ++kk) {
      float af[8], bf[8];
      *(float4*)(af)     = *(const float4*)(&As[kk][ty * 8]);
      *(float4*)(af + 4) = *(const float4*)(&As[kk][ty * 8 + 4]);
      *(float4*)(bf)     = *(const float4*)(&Bs[kk][tx * 8]);
      *(float4*)(bf + 4) = *(const float4*)(&Bs[kk][tx * 8 + 4]);
      #pragma unroll
      for (int i = 0; i < 8; ++i)
        #pragma unroll
        for (int j = 0; j < 8; ++j)
          acc[i][j] = fmaf(af[i], bf[j], acc[i][j]);
    }
  }
  __syncthreads();

  #pragma unroll
  for (int i = 0; i < 8; ++i) {
    int r = row0 + ty * 8 + i;
    float* cp = C + (size_t)r * ldc + col0 + tx * 8;
    #pragma unroll
    for (int j = 0; j < 8; ++j) {
      int c = col0 + tx * 8 + j;
      if (c < Nx) {
        float v = acc[i][j];
        if (bias) v += bias[c];
        if (act == 1) v = fmaxf(v, 0.f) + log1pf(expf(-fabsf(v)));
        cp[j] = v;
      }
    }
  }
}

// ---------------------------------------------------------------------------
// x_proj specialized: dbl(M,64) = u(M,1024) @ w_x(64,1024)^T
// 32 rows/block -> 256 blocks. XBK=32 (12.5 KB LDS).
// ---------------------------------------------------------------------------
#define XBK 32
__global__ __launch_bounds__(256) void xproj_kernel(
    const float* __restrict__ u, const float* __restrict__ wx,
    float* __restrict__ dbl) {
  __shared__ float As[XBK][33];   // [k][row]
  __shared__ float Bs[XBK][65];   // [k][j]
  int tid = threadIdx.x;
  int m0 = blockIdx.x * 32;
  int ty = tid >> 4;
  int tx = tid & 15;
  float acc[2][4];
  #pragma unroll
  for (int i = 0; i < 2; ++i)
    #pragma unroll
    for (int j = 0; j < 4; ++j) acc[i][j] = 0.f;

  for (int k0 = 0; k0 < DIN; k0 += XBK) {
    __syncthreads();
    // stage A: 32 rows x 32 k = 256 float4, 1 per thread
    {
      int row = tid >> 3;
      int kk = (tid & 7) << 2;
      float4 v = *(const float4*)&u[(size_t)(m0 + row) * DIN + k0 + kk];
      As[kk + 0][row] = v.x; As[kk + 1][row] = v.y;
      As[kk + 2][row] = v.z; As[kk + 3][row] = v.w;
    }
    // stage B: 64 j x 32 k = 512 float4, 2 per thread
    #pragma unroll
    for (int rep = 0; rep < 2; ++rep) {
      int f = tid * 2 + rep;
      int j = f >> 3;
      int kk = (f & 7) << 2;
      float4 v = *(const float4*)&wx[(size_t)j * DIN + k0 + kk];
      Bs[kk + 0][j] = v.x; Bs[kk + 1][j] = v.y;
      Bs[kk + 2][j] = v.z; Bs[kk + 3][j] = v.w;
    }
    __syncthreads();
    #pragma unroll 8
    for (int kk = 0; kk < XBK; ++kk) {
      float af0 = As[kk][ty * 2], af1 = As[kk][ty * 2 + 1];
      float bf[4];
      *(float4*)bf = *(const float4*)&Bs[kk][tx * 4];
      #pragma unroll
      for (int j = 0; j < 4; ++j) {
        acc[0][j] = fmaf(af0, bf[j], acc[0][j]);
        acc[1][j] = fmaf(af1, bf[j], acc[1][j]);
      }
    }
  }
  #pragma unroll
  for (int i = 0; i < 2; ++i) {
    float4 v = make_float4(acc[i][0], acc[i][1], acc[i][2], acc[i][3]);
    *(float4*)&dbl[(size_t)(m0 + ty * 2 + i) * 64 + tx * 4] = v;
  }
}

// ---------------------------------------------------------------------------
// dt_proj specialized: delta = softplus(dbl[:,0:32] @ w_dt^T + b_dt) -> xz
// ---------------------------------------------------------------------------
__global__ __launch_bounds__(256) void dtproj_kernel(
    const float* __restrict__ dbl, const float* __restrict__ wdt,
    const float* __restrict__ bdt, float* __restrict__ xz) {
  __shared__ float dsh[8][DTR];
  int tid = threadIdx.x;
  int d = blockIdx.x * 256 + tid;
  int m0 = blockIdx.y * 8;
  {
    int r = tid >> 5, k = tid & 31;
    dsh[r][k] = dbl[(size_t)(m0 + r) * 64 + k];
  }
  float w[DTR];
  #pragma unroll
  for (int q = 0; q < DTR / 4; ++q)
    *(float4*)&w[q * 4] = *(const float4*)&wdt[(size_t)d * DTR + q * 4];
  float bb = bdt[d];
  __syncthreads();
  #pragma unroll
  for (int r = 0; r < 8; ++r) {
    float s = bb;
    #pragma unroll
    for (int k = 0; k < DTR; ++k) s = fmaf(dsh[r][k], w[k], s);
    float v = fmaxf(s, 0.f) + log1pf(expf(-fabsf(s)));  // softplus
    xz[(size_t)(m0 + r) * 2048 + d] = v;
  }
}

// ---------------------------------------------------------------------------
// causal depthwise conv (k=4) + bias + SiLU. Reads xc = xz[:, 0:DIN].
// ---------------------------------------------------------------------------
__global__ __launch_bounds__(256) void conv_kernel(
    const float* __restrict__ xz, const float* __restrict__ cw,
    const float* __restrict__ cb, float* __restrict__ u) {
  int idx = blockIdx.x * 256 + threadIdx.x;
  int d = idx & (DIN - 1);
  int m = idx >> 10;
  int t = m & (Ldim - 1);
  float w0 = cw[d * 4 + 0], w1 = cw[d * 4 + 1], w2 = cw[d * 4 + 2],
        w3 = cw[d * 4 + 3];
  float acc = cb[d];
  if (t >= 3) acc = fmaf(xz[(size_t)(m - 3) * 2048 + d], w0, acc);
  if (t >= 2) acc = fmaf(xz[(size_t)(m - 2) * 2048 + d], w1, acc);
  if (t >= 1) acc = fmaf(xz[(size_t)(m - 1) * 2048 + d], w2, acc);
  acc = fmaf(xz[(size_t)m * 2048 + d], w3, acc);
  u[(size_t)m * DIN + d] = acc / (1.f + __expf(-acc));
}

// ---------------------------------------------------------------------------
// Chunked selective scan pass 1
// ---------------------------------------------------------------------------
__global__ __launch_bounds__(256) void scan1_kernel(
    const float* __restrict__ xz, const float* __restrict__ u,
    const float* __restrict__ dbl, const float* __restrict__ A_log,
    float* __restrict__ Hsum, float* __restrict__ Aprod) {
  __shared__ float Bsh[CHUNK][NST];
  int tid = threadIdx.x;
  int d = blockIdx.x * 256 + tid;
  int c = blockIdx.y;
  int b = blockIdx.z;
  size_t mbase = (size_t)b * Ldim + (size_t)c * CHUNK;
  for (int i = tid; i < CHUNK * NST; i += 256) {
    int t = i >> 4, n = i & 15;
    Bsh[t][n] = dbl[(mbase + t) * 64 + 32 + n];
  }
  float Adn[NST];
  #pragma unroll
  for (int n = 0; n < NST; ++n) Adn[n] = -__expf(A_log[d * NST + n]);
  float h[NST], ap[NST];
  #pragma unroll
  for (int n = 0; n < NST; ++n) { h[n] = 0.f; ap[n] = 1.f; }
  __syncthreads();
  for (int t = 0; t < CHUNK; ++t) {
    size_t m = mbase + t;
    float delta = xz[m * 2048 + d];
    float uv = u[m * DIN + d];
    float du = delta * uv;
    #pragma unroll
    for (int n = 0; n < NST; ++n) {
      float a = __expf(delta * Adn[n]);
      h[n] = fmaf(a, h[n], du * Bsh[t][n]);
      ap[n] *= a;
    }
  }
  size_t base = ((size_t)(b * NCHUNK + c) * NST) * DIN + d;
  #pragma unroll
  for (int n = 0; n < NST; ++n) {
    Hsum[base + (size_t)n * DIN] = h[n];
    Aprod[base + (size_t)n * DIN] = ap[n];
  }
}

// ---------------------------------------------------------------------------
// pass 2: serial carry over the 16 chunks -> exclusive chunk-start state
// ---------------------------------------------------------------------------
__global__ __launch_bounds__(256) void scan2_kernel(
    float* __restrict__ Hsum, const float* __restrict__ Aprod) {
  int idx = blockIdx.x * 256 + threadIdx.x;
  int d = idx & (DIN - 1);
  int bn = idx >> 10;
  int n = bn & 15;
  int b = bn >> 4;
  float carry = 0.f;
  for (int c = 0; c < NCHUNK; ++c) {
    size_t off = ((size_t)((b * NCHUNK + c) * NST + n)) * DIN + d;
    float hs = Hsum[off];
    float apv = Aprod[off];
    Hsum[off] = carry;
    carry = fmaf(apv, carry, hs);
  }
}

// ---------------------------------------------------------------------------
// pass 3: replay with carry, y = C·h + u*Dp, gate silu(z);
// writes y as packed bf16-pair IN PLACE over u (same element index).
// ---------------------------------------------------------------------------
__global__ __launch_bounds__(256) void scan3_kernel(
    const float* __restrict__ xz, float* __restrict__ u,
    const float* __restrict__ dbl, const float* __restrict__ A_log,
    const float* __restrict__ Dp, const float* __restrict__ Hstart) {
  __shared__ float Bsh[CHUNK][NST];
  __shared__ float Csh[CHUNK][NST];
  int tid = threadIdx.x;
  int d = blockIdx.x * 256 + tid;
  int c = blockIdx.y;
  int b = blockIdx.z;
  u32* up = (u32*)u;
  size_t mbase = (size_t)b * Ldim + (size_t)c * CHUNK;
  for (int i = tid; i < CHUNK * NST; i += 256) {
    int t = i >> 4, n = i & 15;
    Bsh[t][n] = dbl[(mbase + t) * 64 + 32 + n];
    Csh[t][n] = dbl[(mbase + t) * 64 + 48 + n];
  }
  float Adn[NST];
  #pragma unroll
  for (int n = 0; n < NST; ++n) Adn[n] = -__expf(A_log[d * NST + n]);
  float h[NST];
  size_t base = ((size_t)(b * NCHUNK + c) * NST) * DIN + d;
  #pragma unroll
  for (int n = 0; n < NST; ++n) h[n] = Hstart[base + (size_t)n * DIN];
  float Dpd = Dp[d];
  __syncthreads();
  for (int t = 0; t < CHUNK; ++t) {
    size_t m = mbase + t;
    float delta = xz[m * 2048 + d];
    float uv = u[m * DIN + d];
    float du = delta * uv;
    float y = 0.f;
    #pragma unroll
    for (int n = 0; n < NST; ++n) {
      float a = __expf(delta * Adn[n]);
      h[n] = fmaf(a, h[n], du * Bsh[t][n]);
      y = fmaf(h[n], Csh[t][n], y);
    }
    float z = xz[m * 2048 + DIN + d];
    float sz = z / (1.f + __expf(-z));
    up[m * DIN + d] = packpair((y + uv * Dpd) * sz);
  }
}

// ---------------------------------------------------------------------------
// maxpool over time + fc
// ---------------------------------------------------------------------------
__global__ __launch_bounds__(256) void pool1_kernel(
    const float* __restrict__ h, float* __restrict__ pm) {
  int b = blockIdx.x, r = blockIdx.y;
  int tid = threadIdx.x;
  #pragma unroll
  for (int rep = 0; rep < 2; ++rep) {
    int j = tid + rep * 256;
    float mx = -1e30f;
    size_t base = ((size_t)b * Ldim + r * 128) * Hdim + j;
    for (int t = 0; t < 128; ++t) mx = fmaxf(mx, h[base + (size_t)t * Hdim]);
    pm[((size_t)b * 8 + r) * Hdim + j] = mx;
  }
}

__global__ __launch_bounds__(256) void pool2_kernel(
    const float* __restrict__ pm, const float* __restrict__ fcw,
    const float* __restrict__ fcb, float* __restrict__ out) {
  int b = blockIdx.x, tid = threadIdx.x;
  float acc = 0.f;
  #pragma unroll
  for (int rep = 0; rep < 2; ++rep) {
    int j = tid + rep * 256;
    float mx = -1e30f;
    for (int r = 0; r < 8; ++r) mx = fmaxf(mx, pm[((size_t)b * 8 + r) * Hdim + j]);
    acc += mx * fcw[j];
  }
  __shared__ float red[256];
  red[tid] = acc;
  __syncthreads();
  for (int s = 128; s > 0; s >>= 1) {
    if (tid < s) red[tid] += red[tid + s];
    __syncthreads();
  }
  if (tid == 0) out[b] = red[0] + fcb[0];
}

// ---------------------------------------------------------------------------
extern "C" void kernel_launch(void* const* d_in, const int* in_sizes, int n_in,
                              void* d_out, int out_size, void* d_ws,
                              size_t ws_size, hipStream_t stream) {
  const float* x         = (const float*)d_in[0];
  const float* ln_g      = (const float*)d_in[1];
  const float* ln_b      = (const float*)d_in[2];
  const float* proj_w    = (const float*)d_in[3];
  const float* proj_b    = (const float*)d_in[4];
  const float* in_proj_w = (const float*)d_in[5];
  const float* conv_w    = (const float*)d_in[6];
  const float* conv_b    = (const float*)d_in[7];
  const float* xproj_w   = (const float*)d_in[8];
  const float* dtproj_w  = (const float*)d_in[9];
  const float* dtproj_b  = (const float*)d_in[10];
  const float* A_log     = (const float*)d_in[11];
  const float* Dp        = (const float*)d_in[12];
  const float* out_pw    = (const float*)d_in[13];
  const float* fc_w      = (const float*)d_in[14];
  const float* fc_b      = (const float*)d_in[15];
  float* out = (float*)d_out;

  float* ws   = (float*)d_ws;
  float* xl   = ws;                                 // M*64
  float* hbuf = xl + (size_t)Mrows * Pdim;          // M*512
  float* xz   = hbuf + (size_t)Mrows * Hdim;        // M*2048
  float* ubuf = xz + (size_t)Mrows * 2 * DIN;       // M*1024
  float* dbl  = ubuf + (size_t)Mrows * DIN;         // M*64
  float* pm   = dbl + (size_t)Mrows * 64;           // 8*8*512
  // scan scratch overlays hbuf (dead between in_proj and out_proj)
  float* Hsum  = hbuf;
  float* Aprod = hbuf + (size_t)Bdim * NCHUNK * NST * DIN;
  // pair buffers:
  //  hpair   : M x 512 u32, overlays ubuf start (dead at layer start;
  //            consumed by in_proj before conv rewrites ubuf)
  //  wpair_in: 2048 x 512 u32, after hpair in ubuf
  //  ypair   : scan3 writes in place over ubuf (u32 per element)
  //  wpair_o : 512 x 1024 u32, overlays xz start (dead after scan3)
  u32* hpair   = (u32*)ubuf;
  u32* wpairin = hpair + (size_t)Mrows * Hdim;
  u32* ypair   = (u32*)ubuf;
  u32* wpairo  = (u32*)xz;

  ln_kernel<<<Mrows / 4, 256, 0, stream>>>(x, ln_g, ln_b, xl);
  gemm_kernel<<<dim3(Hdim / BN, Mrows / BM), 256, 0, stream>>>(
      xl, Pdim, proj_w, hbuf, Hdim, Hdim, Pdim, proj_b, 0);

  for (int l = 0; l < NLdim; ++l) {
    const float* w_in = in_proj_w + (size_t)l * 2 * DIN * Hdim;
    const float* cw   = conv_w + (size_t)l * DIN * 4;
    const float* cb   = conv_b + (size_t)l * DIN;
    const float* w_x  = xproj_w + (size_t)l * 64 * DIN;
    const float* w_dt = dtproj_w + (size_t)l * DIN * DTR;
    const float* b_dt = dtproj_b + (size_t)l * DIN;
    const float* Al   = A_log + (size_t)l * DIN * NST;
    const float* Dl   = Dp + (size_t)l * DIN;
    const float* w_o  = out_pw + (size_t)l * Hdim * DIN;

    // pair-split h and w_in, then xz = h @ w_in^T via pair-MFMA (K'=1024)
    pair_split_kernel<<<Mrows * Hdim / 1024, 256, 0, stream>>>(hbuf, hpair);
    pair_split_kernel<<<2 * DIN * Hdim / 1024, 256, 0, stream>>>(w_in, wpairin);
    gemm_pair<128><<<dim3(2 * DIN / 128, Mrows / 128), 256, 0, stream>>>(
        (const short*)hpair, (const short*)wpairin, xz, 2 * Hdim, 2 * DIN);
    // u = silu(causal_conv(xc) + cb)
    conv_kernel<<<(size_t)Mrows * DIN / 256, 256, 0, stream>>>(xz, cw, cb, ubuf);
    // dbl = u @ w_x^T   (M,64)
    xproj_kernel<<<Mrows / 32, 256, 0, stream>>>(ubuf, w_x, dbl);
    // delta = softplus(dt @ w_dt^T + b_dt) -> xz[:, 0:1024]
    dtproj_kernel<<<dim3(DIN / 256, Mrows / 8), 256, 0, stream>>>(
        dbl, w_dt, b_dt, xz);
    // chunked selective scan; scan3 emits y as bf16-pairs in place
    scan1_kernel<<<dim3(DIN / 256, NCHUNK, Bdim), 256, 0, stream>>>(
        xz, ubuf, dbl, Al, Hsum, Aprod);
    scan2_kernel<<<Bdim * NST * DIN / 256, 256, 0, stream>>>(Hsum, Aprod);
    scan3_kernel<<<dim3(DIN / 256, NCHUNK, Bdim), 256, 0, stream>>>(
        xz, ubuf, dbl, Al, Dl, Hsum);
    // pair-split w_o (xz is dead now), then h = y @ w_out^T (K'=2048)
    pair_split_kernel<<<Hdim * DIN / 1024, 256, 0, stream>>>(w_o, wpairo);
    gemm_pair<64><<<dim3(Hdim / 64, Mrows / 128), 256, 0, stream>>>(
        (const short*)ypair, (const short*)wpairo, hbuf, 2 * DIN, Hdim);
  }

  pool1_kernel<<<dim3(Bdim, 8), 256, 0, stream>>>(hbuf, pm);
  pool2_kernel<<<Bdim, 256, 0, stream>>>(pm, fc_w, fc_b, out);
}